// Round 1
// baseline (3647.716 us; speedup 1.0000x reference)
//
#include <hip/hip_runtime.h>
#include <math.h>

// ---------------------------------------------------------------------------
// KGAT-HAKE: edge attention (HAKE score) -> edge softmax by dst -> 3 layers of
// attention-weighted message passing + dual-GEMM + row-normalize.
// N=100000 nodes (128 feats), E=1000000 edges, R=40 relations, out = N x 240.
// Round 0: correctness-first. Atomics for segment ops; CSR comes later.
// ---------------------------------------------------------------------------

__device__ __forceinline__ void atomicMaxFloat(float* addr, float val) {
    // Works for all sign combinations (IEEE-754 ordering trick).
    if (val >= 0.0f) {
        atomicMax((int*)addr, __float_as_int(val));
    } else {
        atomicMin((unsigned int*)addr, __float_as_uint(val));
    }
}

__global__ void init_kernel(float* __restrict__ amax, float* __restrict__ den, int n) {
    int i = blockIdx.x * blockDim.x + threadIdx.x;
    if (i < n) { amax[i] = -INFINITY; den[i] = 0.0f; }
}

// One 64-lane wave per edge; lane = dimension d in [0,64).
__global__ __launch_bounds__(256) void edge_att_kernel(
    const float* __restrict__ embed, const float* __restrict__ rel,
    const float* __restrict__ pw, const float* __restrict__ mw,
    const int* __restrict__ src, const int* __restrict__ dst,
    const int* __restrict__ etype,
    float* __restrict__ att, float* __restrict__ amax, int nedges)
{
    int e = blockIdx.x * 4 + (threadIdx.x >> 6);
    if (e >= nedges) return;
    int lane = threadIdx.x & 63;
    int s = src[e], d = dst[e], r = etype[e];
    const float* hrow = embed + (size_t)d * 128;
    const float* trow = embed + (size_t)s * 128;
    const float* rrow = rel + (size_t)r * 192;

    float ph = hrow[lane], mh = hrow[64 + lane];
    float pt = trow[lane], mt = trow[64 + lane];
    float pr = rrow[lane];
    float mr = fabsf(rrow[64 + lane]);
    float br = rrow[128 + lane];
    br = fminf(br, 1.0f);
    br = fmaxf(br, -mr);   // where(br < -mr, -mr, br)

    float c = mh * (mr + br) - mt * (1.0f - br);
    float sumsq = c * c;

    // scale = EMB_RANGE / PI  (PI as written in the reference!)
    const float INV_SCALE = (float)(3.1415926235897933 / 0.21875);
    float phase = (ph + pr - pt) * INV_SCALE;
    float psum = fabsf(sinf(0.5f * phase));

    #pragma unroll
    for (int off = 32; off > 0; off >>= 1) {
        sumsq += __shfl_xor(sumsq, off, 64);
        psum  += __shfl_xor(psum, off, 64);
    }
    if (lane == 0) {
        float a = sqrtf(sumsq) * mw[0] + psum * pw[0];
        att[e] = a;
        atomicMaxFloat(&amax[d], a);
    }
}

__global__ void edge_exp_kernel(const int* __restrict__ dst,
                                const float* __restrict__ amax,
                                float* __restrict__ att,
                                float* __restrict__ den, int nedges) {
    int e = blockIdx.x * blockDim.x + threadIdx.x;
    if (e >= nedges) return;
    int d = dst[e];
    float ex = expf(att[e] - amax[d]);
    att[e] = ex;
    atomicAdd(&den[d], ex);
}

__global__ void edge_norm_kernel(const int* __restrict__ dst,
                                 const float* __restrict__ den,
                                 float* __restrict__ att, int nedges) {
    int e = blockIdx.x * blockDim.x + threadIdx.x;
    if (e >= nedges) return;
    att[e] = att[e] / den[dst[e]];
}

// msg = node[src] * att ; Nh[dst] += msg   (float4 gather, scalar atomics)
template<int DIN>
__global__ __launch_bounds__(256) void scatter_kernel(
    const float* __restrict__ node, const float* __restrict__ att,
    const int* __restrict__ src, const int* __restrict__ dst,
    float* __restrict__ Nh, int nedges)
{
    constexpr int CH = DIN / 4;
    long long tid = (long long)blockIdx.x * blockDim.x + threadIdx.x;
    if (tid >= (long long)nedges * CH) return;
    int e = (int)(tid / CH);
    int c = (int)(tid % CH);
    float a = att[e];
    float4 v = *(const float4*)(node + (size_t)src[e] * DIN + (size_t)c * 4);
    float* o = Nh + (size_t)dst[e] * DIN + (size_t)c * 4;
    atomicAdd(o + 0, v.x * a);
    atomicAdd(o + 1, v.y * a);
    atomicAdd(o + 2, v.z * a);
    atomicAdd(o + 3, v.w * a);
}

// o = lrelu((x+Nh)@W1^T + b1) + lrelu((x*Nh)@W2^T + b2); write o (next layer)
// and o/||o|| (to out at column out_col). One wave per node, 4 waves/block,
// grid-stride so weight staging (LDS) is amortized.
template<int DIN, int DOUT>
__global__ __launch_bounds__(256) void node_layer_kernel(
    const float* __restrict__ node, const float* __restrict__ Nh,
    const float* __restrict__ W1, const float* __restrict__ b1,
    const float* __restrict__ W2, const float* __restrict__ b2,
    float* __restrict__ onext, float* __restrict__ out, int out_col, int nnodes)
{
    __shared__ float sW1[DIN * DOUT];   // transposed: sW1[i*DOUT+j] = W1[j][i]
    __shared__ float sW2[DIN * DOUT];
    __shared__ float sb1[DOUT], sb2[DOUT];
    __shared__ float sx[4][2 * DIN];    // per-wave x1 | x2

    for (int idx = threadIdx.x; idx < DIN * DOUT; idx += 256) {
        int j = idx % DOUT, i = idx / DOUT;
        sW1[idx] = W1[(size_t)j * DIN + i];
        sW2[idx] = W2[(size_t)j * DIN + i];
    }
    if (threadIdx.x < DOUT) {
        sb1[threadIdx.x] = b1[threadIdx.x];
        sb2[threadIdx.x] = b2[threadIdx.x];
    }
    __syncthreads();

    int wave = threadIdx.x >> 6, lane = threadIdx.x & 63;
    float* x1 = sx[wave];
    float* x2 = sx[wave] + DIN;

    for (int base = blockIdx.x * 4; base < nnodes; base += gridDim.x * 4) {
        int v = base + wave;
        bool active = v < nnodes;
        if (active) {
            const float* nrow = node + (size_t)v * DIN;
            const float* hrow = Nh + (size_t)v * DIN;
            for (int i = lane; i < DIN; i += 64) {
                float nv = nrow[i], hv = hrow[i];
                x1[i] = nv + hv;
                x2[i] = nv * hv;
            }
        }
        __syncthreads();
        float o = 0.0f;
        if (active && lane < DOUT) {
            float acc1 = sb1[lane], acc2 = sb2[lane];
            #pragma unroll 8
            for (int i = 0; i < DIN; ++i) {
                acc1 += x1[i] * sW1[i * DOUT + lane];
                acc2 += x2[i] * sW2[i * DOUT + lane];
            }
            acc1 = acc1 >= 0.0f ? acc1 : 0.01f * acc1;   // leaky_relu(0.01)
            acc2 = acc2 >= 0.0f ? acc2 : 0.01f * acc2;
            o = acc1 + acc2;
        }
        float ss = o * o;
        #pragma unroll
        for (int off = 32; off > 0; off >>= 1) ss += __shfl_xor(ss, off, 64);
        if (active && lane < DOUT) {
            float inv = 1.0f / fmaxf(sqrtf(ss), 1e-12f);
            if (onext) onext[(size_t)v * DOUT + lane] = o;
            out[(size_t)v * 240 + out_col + lane] = o * inv;
        }
        __syncthreads();
    }
}

__global__ void copy_ego_kernel(const float* __restrict__ embed,
                                float* __restrict__ out, int nnodes) {
    long long tid = (long long)blockIdx.x * blockDim.x + threadIdx.x;
    if (tid >= (long long)nnodes * 128) return;
    int v = (int)(tid >> 7);
    int c = (int)(tid & 127);
    out[(size_t)v * 240 + c] = embed[tid];
}

extern "C" void kernel_launch(void* const* d_in, const int* in_sizes, int n_in,
                              void* d_out, int out_size, void* d_ws, size_t ws_size,
                              hipStream_t stream) {
    const float* embed = (const float*)d_in[0];
    const float* rel   = (const float*)d_in[1];
    const float* pw    = (const float*)d_in[2];
    const float* mw    = (const float*)d_in[3];
    const float* W1_0  = (const float*)d_in[4];
    const float* b1_0  = (const float*)d_in[5];
    const float* W2_0  = (const float*)d_in[6];
    const float* b2_0  = (const float*)d_in[7];
    const float* W1_1  = (const float*)d_in[8];
    const float* b1_1  = (const float*)d_in[9];
    const float* W2_1  = (const float*)d_in[10];
    const float* b2_1  = (const float*)d_in[11];
    const float* W1_2  = (const float*)d_in[12];
    const float* b1_2  = (const float*)d_in[13];
    const float* W1_2b = (const float*)d_in[14];
    const float* b2_2  = (const float*)d_in[15];
    const int* src   = (const int*)d_in[16];
    const int* dst   = (const int*)d_in[17];
    const int* etype = (const int*)d_in[18];
    float* out = (float*)d_out;

    const int n = in_sizes[0] / 128;   // 100000
    const int e = in_sizes[16];        // 1000000

    // workspace layout (all fp32, all fully re-initialized every call)
    char* ws = (char*)d_ws;
    float* att  = (float*)ws;                                   // E
    float* amax = (float*)(ws + (size_t)e * 4);                 // N
    float* den  = amax + n;                                     // N
    float* Nh   = den + n;                                      // N*128 (reused)
    float* o1   = Nh + (size_t)n * 128;                         // N*64
    float* o2   = o1 + (size_t)n * 64;                          // N*32

    init_kernel<<<(n + 255) / 256, 256, 0, stream>>>(amax, den, n);
    edge_att_kernel<<<(e + 3) / 4, 256, 0, stream>>>(embed, rel, pw, mw, src, dst,
                                                     etype, att, amax, e);
    edge_exp_kernel<<<(e + 255) / 256, 256, 0, stream>>>(dst, amax, att, den, e);
    edge_norm_kernel<<<(e + 255) / 256, 256, 0, stream>>>(dst, den, att, e);

    // ---- layer 0: din=128 dout=64 ----
    hipMemsetAsync(Nh, 0, (size_t)n * 128 * 4, stream);
    {
        long long total = (long long)e * (128 / 4);
        scatter_kernel<128><<<(int)((total + 255) / 256), 256, 0, stream>>>(
            embed, att, src, dst, Nh, e);
        node_layer_kernel<128, 64><<<2048, 256, 0, stream>>>(
            embed, Nh, W1_0, b1_0, W2_0, b2_0, o1, out, 128, n);
    }
    // ---- layer 1: din=64 dout=32 ----
    hipMemsetAsync(Nh, 0, (size_t)n * 64 * 4, stream);
    {
        long long total = (long long)e * (64 / 4);
        scatter_kernel<64><<<(int)((total + 255) / 256), 256, 0, stream>>>(
            o1, att, src, dst, Nh, e);
        node_layer_kernel<64, 32><<<2048, 256, 0, stream>>>(
            o1, Nh, W1_1, b1_1, W2_1, b2_1, o2, out, 192, n);
    }
    // ---- layer 2: din=32 dout=16 ----
    hipMemsetAsync(Nh, 0, (size_t)n * 32 * 4, stream);
    {
        long long total = (long long)e * (32 / 4);
        scatter_kernel<32><<<(int)((total + 255) / 256), 256, 0, stream>>>(
            o2, att, src, dst, Nh, e);
        node_layer_kernel<32, 16><<<2048, 256, 0, stream>>>(
            o2, Nh, W1_2, b1_2, W1_2b, b2_2, nullptr, out, 224, n);
    }
    copy_ego_kernel<<<(int)(((long long)n * 128 + 255) / 256), 256, 0, stream>>>(
        embed, out, n);
}

// Round 2
// 1334.059 us; speedup vs baseline: 2.7343x; 2.7343x over previous
//
#include <hip/hip_runtime.h>
#include <math.h>

// ---------------------------------------------------------------------------
// KGAT-HAKE, round 1: CSR-by-dst counting sort per call; gather-based
// aggregation fused with the dual-GEMV node layer. No heavy atomics.
// N=100000 nodes (128 feats), E=1000000 edges, R=40 rels, out = N x 240 fp32.
// ---------------------------------------------------------------------------

// ---- CSR build -------------------------------------------------------------

__global__ void hist_kernel(const int* __restrict__ dst, int* __restrict__ cnt,
                            int nedges) {
    int e = blockIdx.x * blockDim.x + threadIdx.x;
    if (e < nedges) atomicAdd(&cnt[dst[e]], 1);
}

__global__ __launch_bounds__(1024) void scan_kernel(const int* __restrict__ cnt,
                                                    int* __restrict__ rowptr, int n) {
    __shared__ int buf[1024];
    __shared__ int carry_s;
    if (threadIdx.x == 0) { carry_s = 0; rowptr[0] = 0; }
    __syncthreads();
    for (int base = 0; base < n; base += 1024) {
        int i = base + threadIdx.x;
        int v = (i < n) ? cnt[i] : 0;
        buf[threadIdx.x] = v;
        __syncthreads();
        #pragma unroll
        for (int off = 1; off < 1024; off <<= 1) {
            int t = (threadIdx.x >= off) ? buf[threadIdx.x - off] : 0;
            __syncthreads();
            buf[threadIdx.x] += t;
            __syncthreads();
        }
        if (i < n) rowptr[i + 1] = carry_s + buf[threadIdx.x];
        __syncthreads();
        if (threadIdx.x == 0) carry_s += buf[1023];
        __syncthreads();
    }
}

// Scatter edges into dst-sorted slots: att_s (raw score) and src_s.
__global__ void fill_kernel(const int* __restrict__ src, const int* __restrict__ dst,
                            const float* __restrict__ att,
                            const int* __restrict__ rowptr, int* __restrict__ cursor,
                            float* __restrict__ att_s, int* __restrict__ src_s,
                            int nedges) {
    int e = blockIdx.x * blockDim.x + threadIdx.x;
    if (e >= nedges) return;
    int d = dst[e];
    int slot = rowptr[d] + atomicAdd(&cursor[d], 1);
    att_s[slot] = att[e];
    src_s[slot] = src[e];
}

// ---- HAKE edge score (one 64-lane wave per edge) ---------------------------

__global__ __launch_bounds__(256) void edge_att_kernel(
    const float* __restrict__ embed, const float* __restrict__ rel,
    const float* __restrict__ pw, const float* __restrict__ mw,
    const int* __restrict__ src, const int* __restrict__ dst,
    const int* __restrict__ etype,
    float* __restrict__ att, int nedges)
{
    int e = blockIdx.x * 4 + (threadIdx.x >> 6);
    if (e >= nedges) return;
    int lane = threadIdx.x & 63;
    int s = src[e], d = dst[e], r = etype[e];
    const float* hrow = embed + (size_t)d * 128;
    const float* trow = embed + (size_t)s * 128;
    const float* rrow = rel + (size_t)r * 192;

    float ph = hrow[lane], mh = hrow[64 + lane];
    float pt = trow[lane], mt = trow[64 + lane];
    float pr = rrow[lane];
    float mr = fabsf(rrow[64 + lane]);
    float br = rrow[128 + lane];
    br = fminf(br, 1.0f);
    br = fmaxf(br, -mr);          // where(br < -mr, -mr, br)

    float c = mh * (mr + br) - mt * (1.0f - br);
    float sumsq = c * c;

    const float INV_SCALE = (float)(3.1415926235897933 / 0.21875);  // PI/EMB_RANGE
    float phase = (ph + pr - pt) * INV_SCALE;
    float psum = fabsf(sinf(0.5f * phase));

    #pragma unroll
    for (int off = 32; off > 0; off >>= 1) {
        sumsq += __shfl_xor(sumsq, off, 64);
        psum  += __shfl_xor(psum, off, 64);
    }
    if (lane == 0)
        att[e] = sqrtf(sumsq) * mw[0] + psum * pw[0];
}

// ---- per-node softmax over dst-sorted att_s (sequential, no atomics) -------

__global__ void softmax_kernel(const int* __restrict__ rowptr,
                               float* __restrict__ att_s, int nnodes) {
    int v = blockIdx.x * blockDim.x + threadIdx.x;
    if (v >= nnodes) return;
    int beg = rowptr[v], end = rowptr[v + 1];
    if (beg == end) return;
    float m = -INFINITY;
    for (int k = beg; k < end; ++k) m = fmaxf(m, att_s[k]);
    float den = 0.0f;
    for (int k = beg; k < end; ++k) {
        float ex = expf(att_s[k] - m);
        att_s[k] = ex;
        den += ex;
    }
    float inv = 1.0f / den;
    for (int k = beg; k < end; ++k) att_s[k] *= inv;
}

// ---- fused layer: CSR gather-accumulate + dual GEMV + row-normalize --------
// o = lrelu((x+Nh)@W1^T+b1) + lrelu((x*Nh)@W2^T+b2); onext=o; out col = o/||o||
template<int DIN, int DOUT>
__global__ __launch_bounds__(256) void layer_kernel(
    const float* __restrict__ node, const float* __restrict__ att_s,
    const int* __restrict__ src_s, const int* __restrict__ rowptr,
    const float* __restrict__ W1, const float* __restrict__ b1,
    const float* __restrict__ W2, const float* __restrict__ b2,
    float* __restrict__ onext, float* __restrict__ out, int out_col, int nnodes)
{
    __shared__ float sW1[DIN * DOUT];   // transposed: sW1[i*DOUT+j] = W1[j][i]
    __shared__ float sW2[DIN * DOUT];
    __shared__ float sb1[DOUT], sb2[DOUT];
    __shared__ float sx[4][2 * DIN];    // per-wave x1 | x2

    for (int idx = threadIdx.x; idx < DIN * DOUT; idx += 256) {
        int j = idx % DOUT, i = idx / DOUT;
        sW1[idx] = W1[(size_t)j * DIN + i];
        sW2[idx] = W2[(size_t)j * DIN + i];
    }
    if (threadIdx.x < DOUT) {
        sb1[threadIdx.x] = b1[threadIdx.x];
        sb2[threadIdx.x] = b2[threadIdx.x];
    }
    __syncthreads();

    int wave = threadIdx.x >> 6, lane = threadIdx.x & 63;
    constexpr int V = (DIN + 63) / 64;   // floats per lane

    for (int base = blockIdx.x * 4; base < nnodes; base += gridDim.x * 4) {
        int v = base + wave;
        bool active = v < nnodes;
        if (active) {
            float acc[V], nv[V];
            #pragma unroll
            for (int c = 0; c < V; ++c) {
                int i = lane + 64 * c;
                acc[c] = 0.0f;
                nv[c] = (i < DIN) ? node[(size_t)v * DIN + i] : 0.0f;
            }
            int beg = rowptr[v], end = rowptr[v + 1];
            for (int k = beg; k < end; ++k) {
                int s = src_s[k];
                float a = att_s[k];
                const float* srow = node + (size_t)s * DIN;
                #pragma unroll
                for (int c = 0; c < V; ++c) {
                    int i = lane + 64 * c;
                    if (i < DIN) acc[c] += a * srow[i];
                }
            }
            #pragma unroll
            for (int c = 0; c < V; ++c) {
                int i = lane + 64 * c;
                if (i < DIN) {
                    sx[wave][i]       = nv[c] + acc[c];
                    sx[wave][DIN + i] = nv[c] * acc[c];
                }
            }
        }
        __syncthreads();
        float o = 0.0f;
        if (active && lane < DOUT) {
            float a1 = sb1[lane], a2 = sb2[lane];
            const float* x1 = sx[wave];
            const float* x2 = sx[wave] + DIN;
            #pragma unroll 8
            for (int i = 0; i < DIN; ++i) {
                a1 += x1[i] * sW1[i * DOUT + lane];
                a2 += x2[i] * sW2[i * DOUT + lane];
            }
            a1 = a1 >= 0.0f ? a1 : 0.01f * a1;   // leaky_relu
            a2 = a2 >= 0.0f ? a2 : 0.01f * a2;
            o = a1 + a2;
        }
        float ss = o * o;
        #pragma unroll
        for (int off = 32; off > 0; off >>= 1) ss += __shfl_xor(ss, off, 64);
        if (active && lane < DOUT) {
            float inv = 1.0f / fmaxf(sqrtf(ss), 1e-12f);
            if (onext) onext[(size_t)v * DOUT + lane] = o;
            out[(size_t)v * 240 + out_col + lane] = o * inv;
        }
        __syncthreads();
    }
}

__global__ void copy_ego_kernel(const float* __restrict__ embed,
                                float* __restrict__ out, int nnodes) {
    long long tid = (long long)blockIdx.x * blockDim.x + threadIdx.x;
    if (tid >= (long long)nnodes * 128) return;
    int v = (int)(tid >> 7);
    int c = (int)(tid & 127);
    out[(size_t)v * 240 + c] = embed[tid];
}

extern "C" void kernel_launch(void* const* d_in, const int* in_sizes, int n_in,
                              void* d_out, int out_size, void* d_ws, size_t ws_size,
                              hipStream_t stream) {
    const float* embed = (const float*)d_in[0];
    const float* rel   = (const float*)d_in[1];
    const float* pw    = (const float*)d_in[2];
    const float* mw    = (const float*)d_in[3];
    const float* W1_0  = (const float*)d_in[4];
    const float* b1_0  = (const float*)d_in[5];
    const float* W2_0  = (const float*)d_in[6];
    const float* b2_0  = (const float*)d_in[7];
    const float* W1_1  = (const float*)d_in[8];
    const float* b1_1  = (const float*)d_in[9];
    const float* W2_1  = (const float*)d_in[10];
    const float* b2_1  = (const float*)d_in[11];
    const float* W1_2  = (const float*)d_in[12];
    const float* b1_2  = (const float*)d_in[13];
    const float* W1_2b = (const float*)d_in[14];
    const float* b2_2  = (const float*)d_in[15];
    const int* src   = (const int*)d_in[16];
    const int* dst   = (const int*)d_in[17];
    const int* etype = (const int*)d_in[18];
    float* out = (float*)d_out;

    const int n = in_sizes[0] / 128;   // 100000
    const int e = in_sizes[16];        // 1000000

    // workspace layout (all fully re-written every call)
    char* ws = (char*)d_ws;
    float* att    = (float*)ws;                       // E
    float* att_s  = att + e;                          // E (dst-sorted)
    int*   src_s  = (int*)(att_s + e);                // E (dst-sorted)
    int*   rowptr = src_s + e;                        // N+1
    int*   cnt    = rowptr + n + 1;                   // N
    int*   cursor = cnt + n;                          // N
    float* o1     = (float*)(cursor + n);             // N*64
    float* o2     = o1 + (size_t)n * 64;              // N*32

    // CSR build
    hipMemsetAsync(cnt, 0, (size_t)(2 * n) * 4, stream);   // cnt + cursor
    hist_kernel<<<(e + 255) / 256, 256, 0, stream>>>(dst, cnt, e);
    scan_kernel<<<1, 1024, 0, stream>>>(cnt, rowptr, n);

    // edge scores, then sort into CSR slots, then per-node softmax
    edge_att_kernel<<<(e + 3) / 4, 256, 0, stream>>>(embed, rel, pw, mw,
                                                     src, dst, etype, att, e);
    fill_kernel<<<(e + 255) / 256, 256, 0, stream>>>(src, dst, att, rowptr,
                                                     cursor, att_s, src_s, e);
    softmax_kernel<<<(n + 255) / 256, 256, 0, stream>>>(rowptr, att_s, n);

    // fused gather + dual-GEMV layers
    layer_kernel<128, 64><<<2048, 256, 0, stream>>>(
        embed, att_s, src_s, rowptr, W1_0, b1_0, W2_0, b2_0, o1, out, 128, n);
    layer_kernel<64, 32><<<2048, 256, 0, stream>>>(
        o1, att_s, src_s, rowptr, W1_1, b1_1, W2_1, b2_1, o2, out, 192, n);
    layer_kernel<32, 16><<<2048, 256, 0, stream>>>(
        o2, att_s, src_s, rowptr, W1_2, b1_2, W1_2b, b2_2, nullptr, out, 224, n);

    copy_ego_kernel<<<(int)(((long long)n * 128 + 255) / 256), 256, 0, stream>>>(
        embed, out, n);
}

// Round 3
// 962.899 us; speedup vs baseline: 3.7883x; 1.3855x over previous
//
#include <hip/hip_runtime.h>
#include <math.h>

// ---------------------------------------------------------------------------
// KGAT-HAKE, round 3: split latency-bound CSR gather (no LDS, high occupancy,
// float4 + multi-edge MLP) from compute-bound dual-GEMV (LDS weights).
// Unnormalized layer outputs are recovered from d_out via stored row norms.
// N=100000 nodes, E=1000000 edges, R=40 rels, out = N x 240 fp32.
// ---------------------------------------------------------------------------

__global__ void hist_kernel(const int* __restrict__ dst, int* __restrict__ cnt,
                            int nedges) {
    int e = blockIdx.x * blockDim.x + threadIdx.x;
    if (e < nedges) atomicAdd(&cnt[dst[e]], 1);
}

// Single-block prefix sum using wave shuffles (4 barriers per 1024-tile).
__global__ __launch_bounds__(1024) void scan_kernel(const int* __restrict__ cnt,
                                                    int* __restrict__ rowptr, int n) {
    __shared__ int swv[16];
    __shared__ int carry_s;
    int tid = threadIdx.x, lane = tid & 63, wid = tid >> 6;
    if (tid == 0) { carry_s = 0; rowptr[0] = 0; }
    __syncthreads();
    for (int base = 0; base < n; base += 1024) {
        int i = base + tid;
        int v = (i < n) ? cnt[i] : 0;
        #pragma unroll
        for (int off = 1; off < 64; off <<= 1) {
            int t = __shfl_up(v, off, 64);
            if (lane >= off) v += t;
        }
        if (lane == 63) swv[wid] = v;
        __syncthreads();
        if (wid == 0) {
            int s = (lane < 16) ? swv[lane] : 0;
            #pragma unroll
            for (int off = 1; off < 16; off <<= 1) {
                int t = __shfl_up(s, off, 64);
                if (lane >= off) s += t;
            }
            if (lane < 16) swv[lane] = s;
        }
        __syncthreads();
        int offv = carry_s + (wid ? swv[wid - 1] : 0);
        if (i < n) rowptr[i + 1] = v + offv;
        int tot = swv[15];
        __syncthreads();
        if (tid == 0) carry_s += tot;
        __syncthreads();
    }
}

// HAKE edge score, one wave per edge; writes directly into its CSR slot.
__global__ __launch_bounds__(256) void edge_att_kernel(
    const float* __restrict__ embed, const float* __restrict__ rel,
    const float* __restrict__ pw, const float* __restrict__ mw,
    const int* __restrict__ src, const int* __restrict__ dst,
    const int* __restrict__ etype,
    const int* __restrict__ rowptr, int* __restrict__ cursor,
    float* __restrict__ att_s, int* __restrict__ src_s, int nedges)
{
    int e = blockIdx.x * 4 + (threadIdx.x >> 6);
    if (e >= nedges) return;
    int lane = threadIdx.x & 63;
    int s = src[e], d = dst[e], r = etype[e];
    const float* hrow = embed + (size_t)d * 128;
    const float* trow = embed + (size_t)s * 128;
    const float* rrow = rel + (size_t)r * 192;

    float ph = hrow[lane], mh = hrow[64 + lane];
    float pt = trow[lane], mt = trow[64 + lane];
    float pr = rrow[lane];
    float mr = fabsf(rrow[64 + lane]);
    float br = rrow[128 + lane];
    br = fminf(br, 1.0f);
    br = fmaxf(br, -mr);          // where(br < -mr, -mr, br)

    float c = mh * (mr + br) - mt * (1.0f - br);
    float sumsq = c * c;

    const float INV_SCALE = (float)(3.1415926235897933 / 0.21875);  // PI/EMB_RANGE
    float phase = (ph + pr - pt) * INV_SCALE;
    float psum = fabsf(sinf(0.5f * phase));

    #pragma unroll
    for (int off = 32; off > 0; off >>= 1) {
        sumsq += __shfl_xor(sumsq, off, 64);
        psum  += __shfl_xor(psum, off, 64);
    }
    if (lane == 0) {
        float a = sqrtf(sumsq) * mw[0] + psum * pw[0];
        int slot = rowptr[d] + atomicAdd(&cursor[d], 1);
        att_s[slot] = a;
        src_s[slot] = s;
    }
}

// Per-node softmax over dst-sorted scores (sequential, contiguous range).
__global__ void softmax_kernel(const int* __restrict__ rowptr,
                               float* __restrict__ att_s, int nnodes) {
    int v = blockIdx.x * blockDim.x + threadIdx.x;
    if (v >= nnodes) return;
    int beg = rowptr[v], end = rowptr[v + 1];
    if (beg == end) return;
    float m = -INFINITY;
    for (int k = beg; k < end; ++k) m = fmaxf(m, att_s[k]);
    float den = 0.0f;
    for (int k = beg; k < end; ++k) {
        float ex = expf(att_s[k] - m);
        att_s[k] = ex;
        den += ex;
    }
    float inv = 1.0f / den;
    for (int k = beg; k < end; ++k) att_s[k] *= inv;
}

// CSR gather: Nh[v] = sum_k att_s[k] * (node[src_k] * nrm[src_k]).
// Wave per node; DIN/4 lanes per edge (float4), EP edges in parallel, x2 unroll.
template<int DIN>
__global__ __launch_bounds__(256) void gather_kernel(
    const float* __restrict__ node, int nstride, const float* __restrict__ nrm,
    const float* __restrict__ att_s, const int* __restrict__ src_s,
    const int* __restrict__ rowptr, float* __restrict__ Nh, int nnodes)
{
    constexpr int LPE = DIN / 4;    // lanes per edge row
    constexpr int EP  = 64 / LPE;   // edges in parallel
    int v = blockIdx.x * 4 + (threadIdx.x >> 6);
    if (v >= nnodes) return;
    int lane = threadIdx.x & 63;
    int half = lane / LPE;
    int c = lane % LPE;
    int beg = rowptr[v], end = rowptr[v + 1];
    int deg = end - beg;

    float4 acc = make_float4(0.f, 0.f, 0.f, 0.f);
    for (int kbase = 0; kbase < deg; kbase += 64) {
        int kc = kbase + lane;
        int sv = (kc < deg) ? src_s[beg + kc] : 0;     // coalesced index preload
        float av = (kc < deg) ? att_s[beg + kc] : 0.0f;
        int kmax = min(64, deg - kbase);
        for (int kb0 = 0; kb0 < kmax; kb0 += 2 * EP) {
            int ka = kb0 + half;
            int kb = ka + EP;
            bool va = ka < kmax, vb = kb < kmax;
            int ka2 = va ? ka : 0;
            int kb2 = vb ? kb : 0;
            int   sa = __shfl(sv, ka2, 64);
            float aa = __shfl(av, ka2, 64);
            int   sb = __shfl(sv, kb2, 64);
            float ab = __shfl(av, kb2, 64);
            if (!va) aa = 0.0f;
            if (!vb) ab = 0.0f;
            if (nrm) { aa *= nrm[sa]; ab *= nrm[sb]; }
            const float4 ra = *(const float4*)(node + (size_t)sa * nstride + 4 * c);
            const float4 rb = *(const float4*)(node + (size_t)sb * nstride + 4 * c);
            acc.x += aa * ra.x + ab * rb.x;
            acc.y += aa * ra.y + ab * rb.y;
            acc.z += aa * ra.z + ab * rb.z;
            acc.w += aa * ra.w + ab * rb.w;
        }
    }
    #pragma unroll
    for (int off = LPE; off < 64; off <<= 1) {
        acc.x += __shfl_xor(acc.x, off, 64);
        acc.y += __shfl_xor(acc.y, off, 64);
        acc.z += __shfl_xor(acc.z, off, 64);
        acc.w += __shfl_xor(acc.w, off, 64);
    }
    if (half == 0)
        *(float4*)(Nh + (size_t)v * DIN + 4 * c) = acc;
}

// Dual GEMV + leaky_relu + row-normalize. x1/x2 formed in LDS from node & Nh.
// 64/DOUT nodes per wave. Writes normalized row to out and ||o|| to nrm_out.
template<int DIN, int DOUT>
__global__ __launch_bounds__(256) void gemm_kernel(
    const float* __restrict__ node, int nstride, const float* __restrict__ nrm_in,
    const float* __restrict__ Nh,
    const float* __restrict__ W1, const float* __restrict__ b1,
    const float* __restrict__ W2, const float* __restrict__ b2,
    float* __restrict__ out, int out_col, float* __restrict__ nrm_out, int nnodes)
{
    constexpr int NPW = 64 / DOUT;       // nodes per wave
    constexpr int XS  = DIN + 1;         // padded x row (bank-conflict break)
    constexpr int NPB = 4 * NPW;         // nodes per block iteration
    __shared__ float sW1[DIN * DOUT], sW2[DIN * DOUT];   // transposed
    __shared__ float sb1[DOUT], sb2[DOUT];
    __shared__ float sx1[4][NPW * XS], sx2[4][NPW * XS];

    for (int idx = threadIdx.x; idx < DIN * DOUT; idx += 256) {
        int j = idx % DOUT, i = idx / DOUT;
        sW1[idx] = W1[(size_t)j * DIN + i];
        sW2[idx] = W2[(size_t)j * DIN + i];
    }
    if (threadIdx.x < DOUT) {
        sb1[threadIdx.x] = b1[threadIdx.x];
        sb2[threadIdx.x] = b2[threadIdx.x];
    }
    __syncthreads();

    int wave = threadIdx.x >> 6, lane = threadIdx.x & 63;
    int nsub = lane / DOUT, j = lane % DOUT;

    for (int vb = blockIdx.x * NPB; vb < nnodes; vb += gridDim.x * NPB) {
        int vw = vb + wave * NPW;
        for (int t = lane; t < NPW * DIN; t += 64) {
            int r = t / DIN, i = t % DIN;
            int v = vw + r;
            if (v < nnodes) {
                float nv = node[(size_t)v * nstride + i];
                if (nrm_in) nv *= nrm_in[v];
                float h = Nh[(size_t)v * DIN + i];
                sx1[wave][r * XS + i] = nv + h;
                sx2[wave][r * XS + i] = nv * h;
            }
        }
        __syncthreads();
        int v = vw + nsub;
        if (v < nnodes) {
            float a1 = sb1[j], a2 = sb2[j];
            const float* px1 = &sx1[wave][nsub * XS];
            const float* px2 = &sx2[wave][nsub * XS];
            #pragma unroll 8
            for (int i = 0; i < DIN; ++i) {
                a1 += px1[i] * sW1[i * DOUT + j];
                a2 += px2[i] * sW2[i * DOUT + j];
            }
            a1 = a1 >= 0.0f ? a1 : 0.01f * a1;   // leaky_relu
            a2 = a2 >= 0.0f ? a2 : 0.01f * a2;
            float o = a1 + a2;
            float ss = o * o;
            #pragma unroll
            for (int off = 1; off < DOUT; off <<= 1) ss += __shfl_xor(ss, off, 64);
            float nv2 = fmaxf(sqrtf(ss), 1e-12f);
            out[(size_t)v * 240 + out_col + j] = o / nv2;
            if (nrm_out && j == 0) nrm_out[v] = nv2;
        }
        __syncthreads();
    }
}

__global__ void copy_ego_kernel(const float* __restrict__ embed,
                                float* __restrict__ out, int nnodes) {
    long long tid = (long long)blockIdx.x * blockDim.x + threadIdx.x;
    if (tid >= (long long)nnodes * 128) return;
    int v = (int)(tid >> 7);
    int c = (int)(tid & 127);
    out[(size_t)v * 240 + c] = embed[tid];
}

extern "C" void kernel_launch(void* const* d_in, const int* in_sizes, int n_in,
                              void* d_out, int out_size, void* d_ws, size_t ws_size,
                              hipStream_t stream) {
    const float* embed = (const float*)d_in[0];
    const float* rel   = (const float*)d_in[1];
    const float* pw    = (const float*)d_in[2];
    const float* mw    = (const float*)d_in[3];
    const float* W1_0  = (const float*)d_in[4];
    const float* b1_0  = (const float*)d_in[5];
    const float* W2_0  = (const float*)d_in[6];
    const float* b2_0  = (const float*)d_in[7];
    const float* W1_1  = (const float*)d_in[8];
    const float* b1_1  = (const float*)d_in[9];
    const float* W2_1  = (const float*)d_in[10];
    const float* b2_1  = (const float*)d_in[11];
    const float* W1_2  = (const float*)d_in[12];
    const float* b1_2  = (const float*)d_in[13];
    const float* W1_2b = (const float*)d_in[14];
    const float* b2_2  = (const float*)d_in[15];
    const int* src   = (const int*)d_in[16];
    const int* dst   = (const int*)d_in[17];
    const int* etype = (const int*)d_in[18];
    float* out = (float*)d_out;

    const int n = in_sizes[0] / 128;   // 100000
    const int e = in_sizes[16];        // 1000000

    // workspace (~61 MB), every element rewritten each call
    char* ws = (char*)d_ws;
    float* att_s  = (float*)ws;                       // E
    int*   src_s  = (int*)(att_s + e);                // E
    int*   rowptr = src_s + e;                        // N+1
    int*   cnt    = rowptr + n + 1;                   // N
    int*   cursor = cnt + n;                          // N
    float* Nh     = (float*)(cursor + n);             // N*128 (reused per layer)
    float* nrm1   = Nh + (size_t)n * 128;             // N
    float* nrm2   = nrm1 + n;                         // N

    hipMemsetAsync(cnt, 0, (size_t)(2 * n) * 4, stream);   // cnt + cursor
    hist_kernel<<<(e + 255) / 256, 256, 0, stream>>>(dst, cnt, e);
    scan_kernel<<<1, 1024, 0, stream>>>(cnt, rowptr, n);

    edge_att_kernel<<<(e + 3) / 4, 256, 0, stream>>>(
        embed, rel, pw, mw, src, dst, etype, rowptr, cursor, att_s, src_s, e);
    softmax_kernel<<<(n + 255) / 256, 256, 0, stream>>>(rowptr, att_s, n);

    int gblocks = (n + 3) / 4;
    // ---- layer 0: 128 -> 64, out cols [128,192) ----
    gather_kernel<128><<<gblocks, 256, 0, stream>>>(
        embed, 128, nullptr, att_s, src_s, rowptr, Nh, n);
    gemm_kernel<128, 64><<<2048, 256, 0, stream>>>(
        embed, 128, nullptr, Nh, W1_0, b1_0, W2_0, b2_0, out, 128, nrm1, n);
    // ---- layer 1: 64 -> 32, out cols [192,224) ----
    gather_kernel<64><<<gblocks, 256, 0, stream>>>(
        out + 128, 240, nrm1, att_s, src_s, rowptr, Nh, n);
    gemm_kernel<64, 32><<<2048, 256, 0, stream>>>(
        out + 128, 240, nrm1, Nh, W1_1, b1_1, W2_1, b2_1, out, 192, nrm2, n);
    // ---- layer 2: 32 -> 16, out cols [224,240) ----
    gather_kernel<32><<<gblocks, 256, 0, stream>>>(
        out + 192, 240, nrm2, att_s, src_s, rowptr, Nh, n);
    gemm_kernel<32, 16><<<2048, 256, 0, stream>>>(
        out + 192, 240, nrm2, Nh, W1_2, b1_2, W1_2b, b2_2, out, 224, nullptr, n);

    copy_ego_kernel<<<(int)(((long long)n * 128 + 255) / 256), 256, 0, stream>>>(
        embed, out, n);
}

// Round 4
// 944.027 us; speedup vs baseline: 3.8640x; 1.0200x over previous
//
#include <hip/hip_runtime.h>
#include <math.h>

// ---------------------------------------------------------------------------
// KGAT-HAKE, round 4: CSR-order edge scoring (__sinf, no atomics), hierarchical
// scan, register-resident-weight GEMV (s_load uniform x), unrolled gather.
// N=100000 nodes, E=1000000 edges, R=40 rels, out = N x 240 fp32.
// ---------------------------------------------------------------------------

__global__ void hist_kernel(const int* __restrict__ dst, int* __restrict__ cnt,
                            int nedges) {
    int e = blockIdx.x * blockDim.x + threadIdx.x;
    if (e < nedges) atomicAdd(&cnt[dst[e]], 1);
}

// Per-block inclusive scan of cnt -> rowptr[i+1] (block-local) + block sums.
__global__ __launch_bounds__(1024) void scan_block_kernel(
    const int* __restrict__ cnt, int* __restrict__ rowptr,
    int* __restrict__ bsum, int n) {
    __shared__ int swv[16];
    int tid = threadIdx.x, lane = tid & 63, wid = tid >> 6;
    int i = blockIdx.x * 1024 + tid;
    int v = (i < n) ? cnt[i] : 0;
    #pragma unroll
    for (int off = 1; off < 64; off <<= 1) {
        int t = __shfl_up(v, off, 64);
        if (lane >= off) v += t;
    }
    if (lane == 63) swv[wid] = v;
    __syncthreads();
    if (wid == 0) {
        int s = (lane < 16) ? swv[lane] : 0;
        #pragma unroll
        for (int off = 1; off < 16; off <<= 1) {
            int t = __shfl_up(s, off, 64);
            if (lane >= off) s += t;
        }
        if (lane < 16) swv[lane] = s;
    }
    __syncthreads();
    int offv = wid ? swv[wid - 1] : 0;
    if (i < n) rowptr[i + 1] = v + offv;
    if (tid == 1023) bsum[blockIdx.x] = v + offv;
}

// Exclusive scan of up to 128 block sums (one wave, 2 elems/lane).
__global__ __launch_bounds__(64) void scan_tops_kernel(
    const int* __restrict__ bsum, int* __restrict__ boff, int nb) {
    int l = threadIdx.x;
    int a = (2 * l < nb) ? bsum[2 * l] : 0;
    int b = (2 * l + 1 < nb) ? bsum[2 * l + 1] : 0;
    int s = a + b;
    #pragma unroll
    for (int off = 1; off < 64; off <<= 1) {
        int t = __shfl_up(s, off, 64);
        if (l >= off) s += t;
    }
    int excl = s - (a + b);
    if (2 * l < nb) boff[2 * l] = excl;
    if (2 * l + 1 < nb) boff[2 * l + 1] = excl + a;
}

__global__ __launch_bounds__(1024) void scan_add_kernel(
    int* __restrict__ rowptr, const int* __restrict__ boff, int n) {
    int i = blockIdx.x * 1024 + threadIdx.x;
    if (i < n) rowptr[i + 1] += boff[blockIdx.x];
    if (i == 0) rowptr[0] = 0;
}

// Scatter edge metadata into dst-sorted CSR slots (before scoring).
__global__ void fill_kernel(const int* __restrict__ src, const int* __restrict__ dst,
                            const int* __restrict__ etype,
                            const int* __restrict__ rowptr, int* __restrict__ cursor,
                            int* __restrict__ src_s, int* __restrict__ de_s,
                            int nedges) {
    int e = blockIdx.x * blockDim.x + threadIdx.x;
    if (e >= nedges) return;
    int d = dst[e];
    int slot = rowptr[d] + atomicAdd(&cursor[d], 1);
    src_s[slot] = src[e];
    de_s[slot] = d | (etype[e] << 20);
}

// HAKE edge score over CSR-ordered slots; one wave per edge. No atomics.
__global__ __launch_bounds__(256) void edge_att_kernel(
    const float* __restrict__ embed, const float* __restrict__ rel,
    const float* __restrict__ pw, const float* __restrict__ mw,
    const int* __restrict__ src_s, const int* __restrict__ de_s,
    float* __restrict__ att_s, int nedges)
{
    int k = blockIdx.x * 4 + (threadIdx.x >> 6);
    if (k >= nedges) return;
    int ku = __builtin_amdgcn_readfirstlane(k);
    int lane = threadIdx.x & 63;
    int s = src_s[ku];
    int de = de_s[ku];
    int d = de & 0xFFFFF, r = de >> 20;
    const float* hrow = embed + (size_t)d * 128;
    const float* trow = embed + (size_t)s * 128;
    const float* rrow = rel + (size_t)r * 192;

    float ph = hrow[lane], mh = hrow[64 + lane];
    float pt = trow[lane], mt = trow[64 + lane];
    float pr = rrow[lane];
    float mr = fabsf(rrow[64 + lane]);
    float br = rrow[128 + lane];
    br = fminf(br, 1.0f);
    br = fmaxf(br, -mr);          // where(br < -mr, -mr, br)

    float c = mh * (mr + br) - mt * (1.0f - br);
    float sumsq = c * c;

    // phase/2 = (ph+pr-pt) * PI/(2*EMB_RANGE); |arg| <= 3*pi/2 -> native sin ok
    const float HALF_INV_SCALE = (float)(0.5 * 3.1415926235897933 / 0.21875);
    float psum = fabsf(__sinf((ph + pr - pt) * HALF_INV_SCALE));

    #pragma unroll
    for (int off = 32; off > 0; off >>= 1) {
        sumsq += __shfl_xor(sumsq, off, 64);
        psum  += __shfl_xor(psum, off, 64);
    }
    if (lane == 0)
        att_s[ku] = sqrtf(sumsq) * mw[0] + psum * pw[0];
}

// Per-node softmax over dst-sorted scores (contiguous range per node).
__global__ void softmax_kernel(const int* __restrict__ rowptr,
                               float* __restrict__ att_s, int nnodes) {
    int v = blockIdx.x * blockDim.x + threadIdx.x;
    if (v >= nnodes) return;
    int beg = rowptr[v], end = rowptr[v + 1];
    if (beg == end) return;
    float m = -INFINITY;
    for (int kk = beg; kk < end; ++kk) m = fmaxf(m, att_s[kk]);
    float den = 0.0f;
    for (int kk = beg; kk < end; ++kk) {
        float ex = __expf(att_s[kk] - m);
        att_s[kk] = ex;
        den += ex;
    }
    float inv = 1.0f / den;
    for (int kk = beg; kk < end; ++kk) att_s[kk] *= inv;
}

// CSR gather: Nh[v] = sum_k a_k * node[src_k] (a_k optionally * nrm[src_k]).
// Wave per node; DIN/4 lanes per edge (float4), 4-edge-deep unroll for MLP.
template<int DIN, bool NRM>
__global__ __launch_bounds__(256) void gather_kernel(
    const float* __restrict__ node, int nstride, const float* __restrict__ nrm,
    const float* __restrict__ att_s, const int* __restrict__ src_s,
    const int* __restrict__ rowptr, float* __restrict__ Nh, int nnodes)
{
    constexpr int LPE = DIN / 4;    // lanes per edge row
    constexpr int EP  = 64 / LPE;   // edges in parallel
    constexpr int U   = 4;          // unroll depth
    int v = blockIdx.x * 4 + (threadIdx.x >> 6);
    if (v >= nnodes) return;
    int lane = threadIdx.x & 63;
    int sub = lane / LPE;
    int c = lane % LPE;
    int beg = rowptr[v];
    int deg = rowptr[v + 1] - beg;

    float4 acc = make_float4(0.f, 0.f, 0.f, 0.f);
    for (int kb = 0; kb < deg; kb += 64) {
        int kc = kb + lane;
        bool inr = kc < deg;
        int sv = inr ? src_s[beg + kc] : 0;
        float av = inr ? att_s[beg + kc] : 0.0f;
        if (NRM) av = inr ? av * nrm[sv] : 0.0f;   // fold norm at preload
        int kmax = min(64, deg - kb);
        for (int k0 = 0; k0 < kmax; k0 += U * EP) {
            float a[U];
            const float4* p[U];
            #pragma unroll
            for (int u = 0; u < U; ++u) {
                int kk = k0 + u * EP + sub;
                bool val = kk < kmax;
                int kidx = val ? kk : 0;
                int ssrc = __shfl(sv, kidx, 64);
                float aa = __shfl(av, kidx, 64);
                a[u] = val ? aa : 0.0f;
                p[u] = (const float4*)(node + (size_t)ssrc * nstride + 4 * c);
            }
            float4 rv[U];
            #pragma unroll
            for (int u = 0; u < U; ++u) rv[u] = *p[u];
            #pragma unroll
            for (int u = 0; u < U; ++u) {
                acc.x += a[u] * rv[u].x;
                acc.y += a[u] * rv[u].y;
                acc.z += a[u] * rv[u].z;
                acc.w += a[u] * rv[u].w;
            }
        }
    }
    #pragma unroll
    for (int off = LPE; off < 64; off <<= 1) {
        acc.x += __shfl_xor(acc.x, off, 64);
        acc.y += __shfl_xor(acc.y, off, 64);
        acc.z += __shfl_xor(acc.z, off, 64);
        acc.w += __shfl_xor(acc.w, off, 64);
    }
    if (sub == 0)
        *(float4*)(Nh + (size_t)v * DIN + 4 * c) = acc;
}

// Dual GEMV with weights in VGPRs (lane j holds W[j][i-chunk]); x rows read as
// wave-uniform loads. SPLIT waves cooperate per node (i-split), LDS combine.
template<int DIN, int DOUT, int SPLIT, bool NRM>
__global__ __launch_bounds__(256) void gemm_kernel(
    const float* __restrict__ node, int nstride, const float* __restrict__ nrm_in,
    const float* __restrict__ Nh,
    const float* __restrict__ W1, const float* __restrict__ b1,
    const float* __restrict__ W2, const float* __restrict__ b2,
    float* __restrict__ out, int out_col, float* __restrict__ nrm_out, int nnodes)
{
    constexpr int IH  = DIN / SPLIT;   // i-range per wave
    constexpr int NPB = 4 / SPLIT;     // nodes per block iteration
    __shared__ float part[NPB][2][64];
    int wave = threadIdx.x >> 6, lane = threadIdx.x & 63;
    int nw = wave / SPLIT, half = wave % SPLIT;
    int jj = lane & (DOUT - 1);
    int i0 = half * IH;

    float w1r[IH], w2r[IH];
    #pragma unroll
    for (int t = 0; t < IH; t += 4) {
        float4 aq = *(const float4*)(W1 + (size_t)jj * DIN + i0 + t);
        w1r[t] = aq.x; w1r[t + 1] = aq.y; w1r[t + 2] = aq.z; w1r[t + 3] = aq.w;
        float4 bq = *(const float4*)(W2 + (size_t)jj * DIN + i0 + t);
        w2r[t] = bq.x; w2r[t + 1] = bq.y; w2r[t + 2] = bq.z; w2r[t + 3] = bq.w;
    }
    float bb1 = b1[jj], bb2 = b2[jj];

    for (int vb = blockIdx.x * NPB; vb < nnodes; vb += gridDim.x * NPB) {
        int v = vb + nw;
        bool act = v < nnodes;
        float acc1 = 0.0f, acc2 = 0.0f;
        if (act) {
            int vu = __builtin_amdgcn_readfirstlane(v);
            const float* xn = node + (size_t)vu * nstride;
            const float* hr = Nh + (size_t)vu * DIN;
            float rn = NRM ? nrm_in[vu] : 1.0f;
            #pragma unroll
            for (int t = 0; t < IH; ++t) {
                float nv = xn[i0 + t];
                if (NRM) nv *= rn;
                float hh = hr[i0 + t];
                acc1 = fmaf(nv + hh, w1r[t], acc1);
                acc2 = fmaf(nv * hh, w2r[t], acc2);
            }
        }
        if (SPLIT == 2) {
            if (act && half == 1) {
                part[nw][0][lane] = acc1;
                part[nw][1][lane] = acc2;
            }
            __syncthreads();
            if (act && half == 0) {
                acc1 += part[nw][0][lane];
                acc2 += part[nw][1][lane];
            }
        }
        if (act && half == 0) {
            float a1 = acc1 + bb1;
            a1 = a1 >= 0.0f ? a1 : 0.01f * a1;
            float a2 = acc2 + bb2;
            a2 = a2 >= 0.0f ? a2 : 0.01f * a2;
            float o = a1 + a2;
            float ss = o * o;
            #pragma unroll
            for (int off = 1; off < DOUT; off <<= 1) ss += __shfl_xor(ss, off, 64);
            if (lane < DOUT) {
                float nv2 = fmaxf(sqrtf(ss), 1e-12f);
                out[(size_t)v * 240 + out_col + lane] = o / nv2;
                if (nrm_out && lane == 0) nrm_out[v] = nv2;
            }
        }
        if (SPLIT == 2) __syncthreads();
    }
}

__global__ void copy_ego_kernel(const float* __restrict__ embed,
                                float* __restrict__ out, int nnodes) {
    int tid = blockIdx.x * blockDim.x + threadIdx.x;
    if (tid >= nnodes * 32) return;
    int v = tid >> 5;
    int c = tid & 31;
    float4 val = *(const float4*)(embed + (size_t)v * 128 + 4 * c);
    *(float4*)(out + (size_t)v * 240 + 4 * c) = val;
}

extern "C" void kernel_launch(void* const* d_in, const int* in_sizes, int n_in,
                              void* d_out, int out_size, void* d_ws, size_t ws_size,
                              hipStream_t stream) {
    const float* embed = (const float*)d_in[0];
    const float* rel   = (const float*)d_in[1];
    const float* pw    = (const float*)d_in[2];
    const float* mw    = (const float*)d_in[3];
    const float* W1_0  = (const float*)d_in[4];
    const float* b1_0  = (const float*)d_in[5];
    const float* W2_0  = (const float*)d_in[6];
    const float* b2_0  = (const float*)d_in[7];
    const float* W1_1  = (const float*)d_in[8];
    const float* b1_1  = (const float*)d_in[9];
    const float* W2_1  = (const float*)d_in[10];
    const float* b2_1  = (const float*)d_in[11];
    const float* W1_2  = (const float*)d_in[12];
    const float* b1_2  = (const float*)d_in[13];
    const float* W1_2b = (const float*)d_in[14];
    const float* b2_2  = (const float*)d_in[15];
    const int* src   = (const int*)d_in[16];
    const int* dst   = (const int*)d_in[17];
    const int* etype = (const int*)d_in[18];
    float* out = (float*)d_out;

    const int n = in_sizes[0] / 128;   // 100000
    const int e = in_sizes[16];        // 1000000

    // workspace (~65 MB), fully rewritten each call
    char* ws = (char*)d_ws;
    float* att_s  = (float*)ws;                        // E
    int*   src_s  = (int*)(att_s + e);                 // E
    int*   de_s   = src_s + e;                         // E (dst | etype<<20)
    float* Nh     = (float*)(de_s + e);                // N*128 (reused per layer)
    int*   rowptr = (int*)(Nh + (size_t)n * 128);      // N+1
    int*   cnt    = rowptr + n + 1;                    // N
    int*   cursor = cnt + n;                           // N
    int*   bsum   = cursor + n;                        // 128
    int*   boff   = bsum + 128;                        // 128
    float* nrm1   = (float*)(boff + 128);              // N
    float* nrm2   = nrm1 + n;                          // N

    const int NB = (n + 1023) / 1024;   // scan blocks (98)

    hipMemsetAsync(cnt, 0, (size_t)(2 * n) * 4, stream);   // cnt + cursor
    hist_kernel<<<(e + 255) / 256, 256, 0, stream>>>(dst, cnt, e);
    scan_block_kernel<<<NB, 1024, 0, stream>>>(cnt, rowptr, bsum, n);
    scan_tops_kernel<<<1, 64, 0, stream>>>(bsum, boff, NB);
    scan_add_kernel<<<NB, 1024, 0, stream>>>(rowptr, boff, n);
    fill_kernel<<<(e + 255) / 256, 256, 0, stream>>>(src, dst, etype, rowptr,
                                                     cursor, src_s, de_s, e);
    edge_att_kernel<<<(e + 3) / 4, 256, 0, stream>>>(
        embed, rel, pw, mw, src_s, de_s, att_s, e);
    softmax_kernel<<<(n + 255) / 256, 256, 0, stream>>>(rowptr, att_s, n);

    int gblocks = (n + 3) / 4;
    // ---- layer 0: 128 -> 64, out cols [128,192) ----
    gather_kernel<128, false><<<gblocks, 256, 0, stream>>>(
        embed, 128, nullptr, att_s, src_s, rowptr, Nh, n);
    gemm_kernel<128, 64, 2, false><<<2048, 256, 0, stream>>>(
        embed, 128, nullptr, Nh, W1_0, b1_0, W2_0, b2_0, out, 128, nrm1, n);
    // ---- layer 1: 64 -> 32, out cols [192,224) ----
    gather_kernel<64, true><<<gblocks, 256, 0, stream>>>(
        out + 128, 240, nrm1, att_s, src_s, rowptr, Nh, n);
    gemm_kernel<64, 32, 1, true><<<1024, 256, 0, stream>>>(
        out + 128, 240, nrm1, Nh, W1_1, b1_1, W2_1, b2_1, out, 192, nrm2, n);
    // ---- layer 2: 32 -> 16, out cols [224,240) ----
    gather_kernel<32, true><<<gblocks, 256, 0, stream>>>(
        out + 192, 240, nrm2, att_s, src_s, rowptr, Nh, n);
    gemm_kernel<32, 16, 1, true><<<1024, 256, 0, stream>>>(
        out + 192, 240, nrm2, Nh, W1_2, b1_2, W1_2b, b2_2, out, 224, nullptr, n);

    copy_ego_kernel<<<(n * 32 + 255) / 256, 256, 0, stream>>>(embed, out, n);
}

// Round 5
// 914.668 us; speedup vs baseline: 3.9880x; 1.0321x over previous
//
#include <hip/hip_runtime.h>
#include <math.h>

// ---------------------------------------------------------------------------
// KGAT-HAKE, round 5: lane=node GEMV (W via s_load on scalar pipe, 32-64
// independent FMA chains/lane, no cross-lane norm reduce). Gather unchanged.
// N=100000 nodes, E=1000000 edges, R=40 rels, out = N x 240 fp32.
// ---------------------------------------------------------------------------

__global__ void hist_kernel(const int* __restrict__ dst, int* __restrict__ cnt,
                            int nedges) {
    int e = blockIdx.x * blockDim.x + threadIdx.x;
    if (e < nedges) atomicAdd(&cnt[dst[e]], 1);
}

// Per-block inclusive scan of cnt -> rowptr[i+1] (block-local) + block sums.
__global__ __launch_bounds__(1024) void scan_block_kernel(
    const int* __restrict__ cnt, int* __restrict__ rowptr,
    int* __restrict__ bsum, int n) {
    __shared__ int swv[16];
    int tid = threadIdx.x, lane = tid & 63, wid = tid >> 6;
    int i = blockIdx.x * 1024 + tid;
    int v = (i < n) ? cnt[i] : 0;
    #pragma unroll
    for (int off = 1; off < 64; off <<= 1) {
        int t = __shfl_up(v, off, 64);
        if (lane >= off) v += t;
    }
    if (lane == 63) swv[wid] = v;
    __syncthreads();
    if (wid == 0) {
        int s = (lane < 16) ? swv[lane] : 0;
        #pragma unroll
        for (int off = 1; off < 16; off <<= 1) {
            int t = __shfl_up(s, off, 64);
            if (lane >= off) s += t;
        }
        if (lane < 16) swv[lane] = s;
    }
    __syncthreads();
    int offv = wid ? swv[wid - 1] : 0;
    if (i < n) rowptr[i + 1] = v + offv;
    if (tid == 1023) bsum[blockIdx.x] = v + offv;
}

// Exclusive scan of up to 128 block sums (one wave, 2 elems/lane).
__global__ __launch_bounds__(64) void scan_tops_kernel(
    const int* __restrict__ bsum, int* __restrict__ boff, int nb) {
    int l = threadIdx.x;
    int a = (2 * l < nb) ? bsum[2 * l] : 0;
    int b = (2 * l + 1 < nb) ? bsum[2 * l + 1] : 0;
    int s = a + b;
    #pragma unroll
    for (int off = 1; off < 64; off <<= 1) {
        int t = __shfl_up(s, off, 64);
        if (l >= off) s += t;
    }
    int excl = s - (a + b);
    if (2 * l < nb) boff[2 * l] = excl;
    if (2 * l + 1 < nb) boff[2 * l + 1] = excl + a;
}

__global__ __launch_bounds__(1024) void scan_add_kernel(
    int* __restrict__ rowptr, const int* __restrict__ boff, int n) {
    int i = blockIdx.x * 1024 + threadIdx.x;
    if (i < n) rowptr[i + 1] += boff[blockIdx.x];
    if (i == 0) rowptr[0] = 0;
}

// Scatter edge metadata into dst-sorted CSR slots (before scoring).
__global__ void fill_kernel(const int* __restrict__ src, const int* __restrict__ dst,
                            const int* __restrict__ etype,
                            const int* __restrict__ rowptr, int* __restrict__ cursor,
                            int* __restrict__ src_s, int* __restrict__ de_s,
                            int nedges) {
    int e = blockIdx.x * blockDim.x + threadIdx.x;
    if (e >= nedges) return;
    int d = dst[e];
    int slot = rowptr[d] + atomicAdd(&cursor[d], 1);
    src_s[slot] = src[e];
    de_s[slot] = d | (etype[e] << 20);
}

// HAKE edge score over CSR-ordered slots; one wave per edge. No atomics.
__global__ __launch_bounds__(256) void edge_att_kernel(
    const float* __restrict__ embed, const float* __restrict__ rel,
    const float* __restrict__ pw, const float* __restrict__ mw,
    const int* __restrict__ src_s, const int* __restrict__ de_s,
    float* __restrict__ att_s, int nedges)
{
    int k = blockIdx.x * 4 + (threadIdx.x >> 6);
    if (k >= nedges) return;
    int ku = __builtin_amdgcn_readfirstlane(k);
    int lane = threadIdx.x & 63;
    int s = src_s[ku];
    int de = de_s[ku];
    int d = de & 0xFFFFF, r = de >> 20;
    const float* hrow = embed + (size_t)d * 128;
    const float* trow = embed + (size_t)s * 128;
    const float* rrow = rel + (size_t)r * 192;

    float ph = hrow[lane], mh = hrow[64 + lane];
    float pt = trow[lane], mt = trow[64 + lane];
    float pr = rrow[lane];
    float mr = fabsf(rrow[64 + lane]);
    float br = rrow[128 + lane];
    br = fminf(br, 1.0f);
    br = fmaxf(br, -mr);          // where(br < -mr, -mr, br)

    float c = mh * (mr + br) - mt * (1.0f - br);
    float sumsq = c * c;

    // phase/2 = (ph+pr-pt) * PI/(2*EMB_RANGE); |arg| <= 3*pi/2 -> native sin ok
    const float HALF_INV_SCALE = (float)(0.5 * 3.1415926235897933 / 0.21875);
    float psum = fabsf(__sinf((ph + pr - pt) * HALF_INV_SCALE));

    #pragma unroll
    for (int off = 32; off > 0; off >>= 1) {
        sumsq += __shfl_xor(sumsq, off, 64);
        psum  += __shfl_xor(psum, off, 64);
    }
    if (lane == 0)
        att_s[ku] = sqrtf(sumsq) * mw[0] + psum * pw[0];
}

// Per-node softmax over dst-sorted scores (contiguous range per node).
__global__ void softmax_kernel(const int* __restrict__ rowptr,
                               float* __restrict__ att_s, int nnodes) {
    int v = blockIdx.x * blockDim.x + threadIdx.x;
    if (v >= nnodes) return;
    int beg = rowptr[v], end = rowptr[v + 1];
    if (beg == end) return;
    float m = -INFINITY;
    for (int kk = beg; kk < end; ++kk) m = fmaxf(m, att_s[kk]);
    float den = 0.0f;
    for (int kk = beg; kk < end; ++kk) {
        float ex = __expf(att_s[kk] - m);
        att_s[kk] = ex;
        den += ex;
    }
    float inv = 1.0f / den;
    for (int kk = beg; kk < end; ++kk) att_s[kk] *= inv;
}

// CSR gather: Nh[v] = sum_k a_k * node[src_k] (a_k optionally * nrm[src_k]).
// Wave per node; DIN/4 lanes per edge (float4), 4-edge-deep unroll for MLP.
template<int DIN, bool NRM>
__global__ __launch_bounds__(256) void gather_kernel(
    const float* __restrict__ node, int nstride, const float* __restrict__ nrm,
    const float* __restrict__ att_s, const int* __restrict__ src_s,
    const int* __restrict__ rowptr, float* __restrict__ Nh, int nnodes)
{
    constexpr int LPE = DIN / 4;    // lanes per edge row
    constexpr int EP  = 64 / LPE;   // edges in parallel
    constexpr int U   = 4;          // unroll depth
    int v = blockIdx.x * 4 + (threadIdx.x >> 6);
    if (v >= nnodes) return;
    int lane = threadIdx.x & 63;
    int sub = lane / LPE;
    int c = lane % LPE;
    int beg = rowptr[v];
    int deg = rowptr[v + 1] - beg;

    float4 acc = make_float4(0.f, 0.f, 0.f, 0.f);
    for (int kb = 0; kb < deg; kb += 64) {
        int kc = kb + lane;
        bool inr = kc < deg;
        int sv = inr ? src_s[beg + kc] : 0;
        float av = inr ? att_s[beg + kc] : 0.0f;
        if (NRM) av = inr ? av * nrm[sv] : 0.0f;   // fold norm at preload
        int kmax = min(64, deg - kb);
        for (int k0 = 0; k0 < kmax; k0 += U * EP) {
            float a[U];
            const float4* p[U];
            #pragma unroll
            for (int u = 0; u < U; ++u) {
                int kk = k0 + u * EP + sub;
                bool val = kk < kmax;
                int kidx = val ? kk : 0;
                int ssrc = __shfl(sv, kidx, 64);
                float aa = __shfl(av, kidx, 64);
                a[u] = val ? aa : 0.0f;
                p[u] = (const float4*)(node + (size_t)ssrc * nstride + 4 * c);
            }
            float4 rv[U];
            #pragma unroll
            for (int u = 0; u < U; ++u) rv[u] = *p[u];
            #pragma unroll
            for (int u = 0; u < U; ++u) {
                acc.x += a[u] * rv[u].x;
                acc.y += a[u] * rv[u].y;
                acc.z += a[u] * rv[u].z;
                acc.w += a[u] * rv[u].w;
            }
        }
    }
    #pragma unroll
    for (int off = LPE; off < 64; off <<= 1) {
        acc.x += __shfl_xor(acc.x, off, 64);
        acc.y += __shfl_xor(acc.y, off, 64);
        acc.z += __shfl_xor(acc.z, off, 64);
        acc.w += __shfl_xor(acc.w, off, 64);
    }
    if (sub == 0)
        *(float4*)(Nh + (size_t)v * DIN + 4 * c) = acc;
}

// Dual GEMV, lane = node. Wave handles 64 consecutive nodes; j,i are loops.
// W reads are wave-uniform -> scalar pipe; acc[DH] = independent FMA chains.
// JSPLIT waves share a tile (split on j); one LDS combine for the norm.
template<int DIN, int DOUT, int JSPLIT, bool NRM>
__global__ __launch_bounds__(256) void gemm_kernel(
    const float* __restrict__ node, int nstride, const float* __restrict__ nrm_in,
    const float* __restrict__ Nh,
    const float* __restrict__ W1, const float* __restrict__ b1,
    const float* __restrict__ W2, const float* __restrict__ b2,
    float* __restrict__ out, int out_col, float* __restrict__ nrm_out, int nnodes)
{
    constexpr int DH = DOUT / JSPLIT;   // j-range per wave
    constexpr int GRP = 4 / JSPLIT;     // tiles per block
    __shared__ float sred[GRP][JSPLIT][64];
    int lane = threadIdx.x & 63;
    int wib = threadIdx.x >> 6;
    int grp = wib / JSPLIT;
    int jh = wib % JSPLIT;
    int tile = blockIdx.x * GRP + grp;
    int v = tile * 64 + lane;
    bool act = v < nnodes;
    int vc = act ? v : (nnodes - 1);
    int j0 = jh * DH;

    const float* pn = node + (size_t)vc * nstride;
    const float* ph = Nh + (size_t)vc * DIN;
    float rn = NRM ? nrm_in[vc] : 1.0f;

    float acc1[DH], acc2[DH];
    #pragma unroll
    for (int j = 0; j < DH; ++j) { acc1[j] = 0.f; acc2[j] = 0.f; }

    #pragma unroll 1
    for (int ic = 0; ic < DIN; ic += 8) {
        float4 n0 = *(const float4*)(pn + ic);
        float4 n1 = *(const float4*)(pn + ic + 4);
        float4 h0 = *(const float4*)(ph + ic);
        float4 h1 = *(const float4*)(ph + ic + 4);
        float nvv[8] = {n0.x, n0.y, n0.z, n0.w, n1.x, n1.y, n1.z, n1.w};
        float hvv[8] = {h0.x, h0.y, h0.z, h0.w, h1.x, h1.y, h1.z, h1.w};
        float x1c[8], x2c[8];
        #pragma unroll
        for (int t = 0; t < 8; ++t) {
            float nv = NRM ? nvv[t] * rn : nvv[t];
            x1c[t] = nv + hvv[t];
            x2c[t] = nv * hvv[t];
        }
        #pragma unroll
        for (int j = 0; j < DH; ++j) {
            const float* w1 = W1 + (size_t)(j0 + j) * DIN + ic;  // uniform -> s_load
            const float* w2 = W2 + (size_t)(j0 + j) * DIN + ic;
            #pragma unroll
            for (int t = 0; t < 8; ++t) {
                acc1[j] = fmaf(x1c[t], w1[t], acc1[j]);
                acc2[j] = fmaf(x2c[t], w2[t], acc2[j]);
            }
        }
    }

    float o[DH];
    float ss = 0.0f;
    #pragma unroll
    for (int j = 0; j < DH; ++j) {
        float a1 = acc1[j] + b1[j0 + j];
        a1 = a1 >= 0.0f ? a1 : 0.01f * a1;   // leaky_relu
        float a2 = acc2[j] + b2[j0 + j];
        a2 = a2 >= 0.0f ? a2 : 0.01f * a2;
        o[j] = a1 + a2;
        ss += o[j] * o[j];
    }
    if (JSPLIT > 1) {
        sred[grp][jh][lane] = ss;
        __syncthreads();
        float tot = 0.0f;
        #pragma unroll
        for (int q = 0; q < JSPLIT; ++q) tot += sred[grp][q][lane];
        ss = tot;
    }
    float nv2 = fmaxf(sqrtf(ss), 1e-12f);
    float inv = 1.0f / nv2;
    if (act) {
        #pragma unroll
        for (int j = 0; j < DH; j += 4) {
            float4 st = make_float4(o[j] * inv, o[j + 1] * inv,
                                    o[j + 2] * inv, o[j + 3] * inv);
            *(float4*)(out + (size_t)v * 240 + out_col + j0 + j) = st;
        }
        if (nrm_out && jh == 0) nrm_out[v] = nv2;
    }
}

__global__ void copy_ego_kernel(const float* __restrict__ embed,
                                float* __restrict__ out, int nnodes) {
    int tid = blockIdx.x * blockDim.x + threadIdx.x;
    if (tid >= nnodes * 32) return;
    int v = tid >> 5;
    int c = tid & 31;
    float4 val = *(const float4*)(embed + (size_t)v * 128 + 4 * c);
    *(float4*)(out + (size_t)v * 240 + 4 * c) = val;
}

extern "C" void kernel_launch(void* const* d_in, const int* in_sizes, int n_in,
                              void* d_out, int out_size, void* d_ws, size_t ws_size,
                              hipStream_t stream) {
    const float* embed = (const float*)d_in[0];
    const float* rel   = (const float*)d_in[1];
    const float* pw    = (const float*)d_in[2];
    const float* mw    = (const float*)d_in[3];
    const float* W1_0  = (const float*)d_in[4];
    const float* b1_0  = (const float*)d_in[5];
    const float* W2_0  = (const float*)d_in[6];
    const float* b2_0  = (const float*)d_in[7];
    const float* W1_1  = (const float*)d_in[8];
    const float* b1_1  = (const float*)d_in[9];
    const float* W2_1  = (const float*)d_in[10];
    const float* b2_1  = (const float*)d_in[11];
    const float* W1_2  = (const float*)d_in[12];
    const float* b1_2  = (const float*)d_in[13];
    const float* W1_2b = (const float*)d_in[14];
    const float* b2_2  = (const float*)d_in[15];
    const int* src   = (const int*)d_in[16];
    const int* dst   = (const int*)d_in[17];
    const int* etype = (const int*)d_in[18];
    float* out = (float*)d_out;

    const int n = in_sizes[0] / 128;   // 100000
    const int e = in_sizes[16];        // 1000000

    // workspace (~65 MB), fully rewritten each call
    char* ws = (char*)d_ws;
    float* att_s  = (float*)ws;                        // E
    int*   src_s  = (int*)(att_s + e);                 // E
    int*   de_s   = src_s + e;                         // E (dst | etype<<20)
    float* Nh     = (float*)(de_s + e);                // N*128 (reused per layer)
    int*   rowptr = (int*)(Nh + (size_t)n * 128);      // N+1
    int*   cnt    = rowptr + n + 1;                    // N
    int*   cursor = cnt + n;                           // N
    int*   bsum   = cursor + n;                        // 128
    int*   boff   = bsum + 128;                        // 128
    float* nrm1   = (float*)(boff + 128);              // N
    float* nrm2   = nrm1 + n;                          // N

    const int NB = (n + 1023) / 1024;   // scan blocks (98)

    hipMemsetAsync(cnt, 0, (size_t)(2 * n) * 4, stream);   // cnt + cursor
    hist_kernel<<<(e + 255) / 256, 256, 0, stream>>>(dst, cnt, e);
    scan_block_kernel<<<NB, 1024, 0, stream>>>(cnt, rowptr, bsum, n);
    scan_tops_kernel<<<1, 64, 0, stream>>>(bsum, boff, NB);
    scan_add_kernel<<<NB, 1024, 0, stream>>>(rowptr, boff, n);
    fill_kernel<<<(e + 255) / 256, 256, 0, stream>>>(src, dst, etype, rowptr,
                                                     cursor, src_s, de_s, e);
    edge_att_kernel<<<(e + 3) / 4, 256, 0, stream>>>(
        embed, rel, pw, mw, src_s, de_s, att_s, e);
    softmax_kernel<<<(n + 255) / 256, 256, 0, stream>>>(rowptr, att_s, n);

    int gblocks = (n + 3) / 4;
    int tiles = (n + 63) / 64;          // 1563 node tiles (64 nodes per wave)
    // ---- layer 0: 128 -> 64, out cols [128,192) ----
    gather_kernel<128, false><<<gblocks, 256, 0, stream>>>(
        embed, 128, nullptr, att_s, src_s, rowptr, Nh, n);
    gemm_kernel<128, 64, 2, false><<<(tiles + 1) / 2, 256, 0, stream>>>(
        embed, 128, nullptr, Nh, W1_0, b1_0, W2_0, b2_0, out, 128, nrm1, n);
    // ---- layer 1: 64 -> 32, out cols [192,224) ----
    gather_kernel<64, true><<<gblocks, 256, 0, stream>>>(
        out + 128, 240, nrm1, att_s, src_s, rowptr, Nh, n);
    gemm_kernel<64, 32, 2, true><<<(tiles + 1) / 2, 256, 0, stream>>>(
        out + 128, 240, nrm1, Nh, W1_1, b1_1, W2_1, b2_1, out, 192, nrm2, n);
    // ---- layer 2: 32 -> 16, out cols [224,240) ----
    gather_kernel<32, true><<<gblocks, 256, 0, stream>>>(
        out + 192, 240, nrm2, att_s, src_s, rowptr, Nh, n);
    gemm_kernel<32, 16, 1, true><<<(tiles + 3) / 4, 256, 0, stream>>>(
        out + 192, 240, nrm2, Nh, W1_2, b1_2, W1_2b, b2_2, out, 224, nullptr, n);

    copy_ego_kernel<<<(n * 32 + 255) / 256, 256, 0, stream>>>(embed, out, n);
}

// Round 6
// 908.866 us; speedup vs baseline: 4.0135x; 1.0064x over previous
//
#include <hip/hip_runtime.h>
#include <math.h>

// ---------------------------------------------------------------------------
// KGAT-HAKE, round 6: gemm rebuilt as lane=node, wave owns ALL output j's.
// W addresses involve only kernel args + loop counters -> guaranteed s_load
// (scalar pipe); v_fmac v_acc, s_w, v_x; no LDS, no barriers, norm lane-local.
// N=100000 nodes, E=1000000 edges, R=40 rels, out = N x 240 fp32.
// ---------------------------------------------------------------------------

__global__ void hist_kernel(const int* __restrict__ dst, int* __restrict__ cnt,
                            int nedges) {
    int e = blockIdx.x * blockDim.x + threadIdx.x;
    if (e < nedges) atomicAdd(&cnt[dst[e]], 1);
}

// Per-block inclusive scan of cnt -> rowptr[i+1] (block-local) + block sums.
__global__ __launch_bounds__(1024) void scan_block_kernel(
    const int* __restrict__ cnt, int* __restrict__ rowptr,
    int* __restrict__ bsum, int n) {
    __shared__ int swv[16];
    int tid = threadIdx.x, lane = tid & 63, wid = tid >> 6;
    int i = blockIdx.x * 1024 + tid;
    int v = (i < n) ? cnt[i] : 0;
    #pragma unroll
    for (int off = 1; off < 64; off <<= 1) {
        int t = __shfl_up(v, off, 64);
        if (lane >= off) v += t;
    }
    if (lane == 63) swv[wid] = v;
    __syncthreads();
    if (wid == 0) {
        int s = (lane < 16) ? swv[lane] : 0;
        #pragma unroll
        for (int off = 1; off < 16; off <<= 1) {
            int t = __shfl_up(s, off, 64);
            if (lane >= off) s += t;
        }
        if (lane < 16) swv[lane] = s;
    }
    __syncthreads();
    int offv = wid ? swv[wid - 1] : 0;
    if (i < n) rowptr[i + 1] = v + offv;
    if (tid == 1023) bsum[blockIdx.x] = v + offv;
}

// Exclusive scan of up to 128 block sums (one wave, 2 elems/lane).
__global__ __launch_bounds__(64) void scan_tops_kernel(
    const int* __restrict__ bsum, int* __restrict__ boff, int nb) {
    int l = threadIdx.x;
    int a = (2 * l < nb) ? bsum[2 * l] : 0;
    int b = (2 * l + 1 < nb) ? bsum[2 * l + 1] : 0;
    int s = a + b;
    #pragma unroll
    for (int off = 1; off < 64; off <<= 1) {
        int t = __shfl_up(s, off, 64);
        if (l >= off) s += t;
    }
    int excl = s - (a + b);
    if (2 * l < nb) boff[2 * l] = excl;
    if (2 * l + 1 < nb) boff[2 * l + 1] = excl + a;
}

__global__ __launch_bounds__(1024) void scan_add_kernel(
    int* __restrict__ rowptr, const int* __restrict__ boff, int n) {
    int i = blockIdx.x * 1024 + threadIdx.x;
    if (i < n) rowptr[i + 1] += boff[blockIdx.x];
    if (i == 0) rowptr[0] = 0;
}

// Scatter edge metadata into dst-sorted CSR slots (before scoring).
__global__ void fill_kernel(const int* __restrict__ src, const int* __restrict__ dst,
                            const int* __restrict__ etype,
                            const int* __restrict__ rowptr, int* __restrict__ cursor,
                            int* __restrict__ src_s, int* __restrict__ de_s,
                            int nedges) {
    int e = blockIdx.x * blockDim.x + threadIdx.x;
    if (e >= nedges) return;
    int d = dst[e];
    int slot = rowptr[d] + atomicAdd(&cursor[d], 1);
    src_s[slot] = src[e];
    de_s[slot] = d | (etype[e] << 20);
}

// HAKE edge score over CSR-ordered slots; one wave per edge. No atomics.
__global__ __launch_bounds__(256) void edge_att_kernel(
    const float* __restrict__ embed, const float* __restrict__ rel,
    const float* __restrict__ pw, const float* __restrict__ mw,
    const int* __restrict__ src_s, const int* __restrict__ de_s,
    float* __restrict__ att_s, int nedges)
{
    int k = blockIdx.x * 4 + (threadIdx.x >> 6);
    if (k >= nedges) return;
    int ku = __builtin_amdgcn_readfirstlane(k);
    int lane = threadIdx.x & 63;
    int s = src_s[ku];
    int de = de_s[ku];
    int d = de & 0xFFFFF, r = de >> 20;
    const float* hrow = embed + (size_t)d * 128;
    const float* trow = embed + (size_t)s * 128;
    const float* rrow = rel + (size_t)r * 192;

    float ph = hrow[lane], mh = hrow[64 + lane];
    float pt = trow[lane], mt = trow[64 + lane];
    float pr = rrow[lane];
    float mr = fabsf(rrow[64 + lane]);
    float br = rrow[128 + lane];
    br = fminf(br, 1.0f);
    br = fmaxf(br, -mr);          // where(br < -mr, -mr, br)

    float c = mh * (mr + br) - mt * (1.0f - br);
    float sumsq = c * c;

    // phase/2 = (ph+pr-pt) * PI/(2*EMB_RANGE); |arg| <= 3*pi/2 -> native sin ok
    const float HALF_INV_SCALE = (float)(0.5 * 3.1415926235897933 / 0.21875);
    float psum = fabsf(__sinf((ph + pr - pt) * HALF_INV_SCALE));

    #pragma unroll
    for (int off = 32; off > 0; off >>= 1) {
        sumsq += __shfl_xor(sumsq, off, 64);
        psum  += __shfl_xor(psum, off, 64);
    }
    if (lane == 0)
        att_s[ku] = sqrtf(sumsq) * mw[0] + psum * pw[0];
}

// Per-node softmax over dst-sorted scores (contiguous range per node).
__global__ void softmax_kernel(const int* __restrict__ rowptr,
                               float* __restrict__ att_s, int nnodes) {
    int v = blockIdx.x * blockDim.x + threadIdx.x;
    if (v >= nnodes) return;
    int beg = rowptr[v], end = rowptr[v + 1];
    if (beg == end) return;
    float m = -INFINITY;
    for (int kk = beg; kk < end; ++kk) m = fmaxf(m, att_s[kk]);
    float den = 0.0f;
    for (int kk = beg; kk < end; ++kk) {
        float ex = __expf(att_s[kk] - m);
        att_s[kk] = ex;
        den += ex;
    }
    float inv = 1.0f / den;
    for (int kk = beg; kk < end; ++kk) att_s[kk] *= inv;
}

// CSR gather: Nh[v] = sum_k a_k * node[src_k] (a_k optionally * nrm[src_k]).
// Wave per node; DIN/4 lanes per edge (float4), 4-edge-deep unroll for MLP.
template<int DIN, bool NRM>
__global__ __launch_bounds__(256) void gather_kernel(
    const float* __restrict__ node, int nstride, const float* __restrict__ nrm,
    const float* __restrict__ att_s, const int* __restrict__ src_s,
    const int* __restrict__ rowptr, float* __restrict__ Nh, int nnodes)
{
    constexpr int LPE = DIN / 4;    // lanes per edge row
    constexpr int EP  = 64 / LPE;   // edges in parallel
    constexpr int U   = 4;          // unroll depth
    int v = blockIdx.x * 4 + (threadIdx.x >> 6);
    if (v >= nnodes) return;
    int lane = threadIdx.x & 63;
    int sub = lane / LPE;
    int c = lane % LPE;
    int beg = rowptr[v];
    int deg = rowptr[v + 1] - beg;

    float4 acc = make_float4(0.f, 0.f, 0.f, 0.f);
    for (int kb = 0; kb < deg; kb += 64) {
        int kc = kb + lane;
        bool inr = kc < deg;
        int sv = inr ? src_s[beg + kc] : 0;
        float av = inr ? att_s[beg + kc] : 0.0f;
        if (NRM) av = inr ? av * nrm[sv] : 0.0f;   // fold norm at preload
        int kmax = min(64, deg - kb);
        for (int k0 = 0; k0 < kmax; k0 += U * EP) {
            float a[U];
            const float4* p[U];
            #pragma unroll
            for (int u = 0; u < U; ++u) {
                int kk = k0 + u * EP + sub;
                bool val = kk < kmax;
                int kidx = val ? kk : 0;
                int ssrc = __shfl(sv, kidx, 64);
                float aa = __shfl(av, kidx, 64);
                a[u] = val ? aa : 0.0f;
                p[u] = (const float4*)(node + (size_t)ssrc * nstride + 4 * c);
            }
            float4 rv[U];
            #pragma unroll
            for (int u = 0; u < U; ++u) rv[u] = *p[u];
            #pragma unroll
            for (int u = 0; u < U; ++u) {
                acc.x += a[u] * rv[u].x;
                acc.y += a[u] * rv[u].y;
                acc.z += a[u] * rv[u].z;
                acc.w += a[u] * rv[u].w;
            }
        }
    }
    #pragma unroll
    for (int off = LPE; off < 64; off <<= 1) {
        acc.x += __shfl_xor(acc.x, off, 64);
        acc.y += __shfl_xor(acc.y, off, 64);
        acc.z += __shfl_xor(acc.z, off, 64);
        acc.w += __shfl_xor(acc.w, off, 64);
    }
    if (sub == 0)
        *(float4*)(Nh + (size_t)v * DIN + 4 * c) = acc;
}

// Dual GEMV, lane = node, wave owns ALL DOUT outputs of its 64 nodes.
// W address = kernel arg + loop counters only -> s_load on scalar pipe;
// FMA = v_fmac v_acc, s_w, v_x. No LDS, no barriers; norm is lane-local.
template<int DIN, int DOUT, bool NRM>
__global__ __launch_bounds__(256) void gemm_kernel(
    const float* __restrict__ node, int nstride, const float* __restrict__ nrm_in,
    const float* __restrict__ Nh,
    const float* __restrict__ W1, const float* __restrict__ b1,
    const float* __restrict__ W2, const float* __restrict__ b2,
    float* __restrict__ out, int out_col, float* __restrict__ nrm_out, int nnodes)
{
    int lane = threadIdx.x & 63;
    int tile = blockIdx.x * 4 + (threadIdx.x >> 6);
    int v = tile * 64 + lane;
    bool act = v < nnodes;
    int vc = act ? v : (nnodes - 1);

    const float* pn = node + (size_t)vc * nstride;
    const float* ph = Nh + (size_t)vc * DIN;
    float rn = NRM ? nrm_in[vc] : 1.0f;

    float acc1[DOUT], acc2[DOUT];
    #pragma unroll
    for (int j = 0; j < DOUT; ++j) { acc1[j] = 0.f; acc2[j] = 0.f; }

    #pragma unroll 1
    for (int ic = 0; ic < DIN; ic += 8) {
        float4 n0 = *(const float4*)(pn + ic);
        float4 n1 = *(const float4*)(pn + ic + 4);
        float4 h0 = *(const float4*)(ph + ic);
        float4 h1 = *(const float4*)(ph + ic + 4);
        float nvv[8] = {n0.x, n0.y, n0.z, n0.w, n1.x, n1.y, n1.z, n1.w};
        float hvv[8] = {h0.x, h0.y, h0.z, h0.w, h1.x, h1.y, h1.z, h1.w};
        float x1c[8], x2c[8];
        #pragma unroll
        for (int t = 0; t < 8; ++t) {
            float nv = NRM ? nvv[t] * rn : nvv[t];
            x1c[t] = nv + hvv[t];
            x2c[t] = nv * hvv[t];
        }
        #pragma unroll
        for (int j = 0; j < DOUT; ++j) {
            // wave-uniform addresses (args + loop counters) -> s_load
            const float* w1 = W1 + (size_t)j * DIN + ic;
            const float* w2 = W2 + (size_t)j * DIN + ic;
            #pragma unroll
            for (int t = 0; t < 8; ++t) {
                acc1[j] = fmaf(x1c[t], w1[t], acc1[j]);
                acc2[j] = fmaf(x2c[t], w2[t], acc2[j]);
            }
        }
    }

    float ss = 0.0f;
    #pragma unroll
    for (int j = 0; j < DOUT; ++j) {
        float a1 = acc1[j] + b1[j];
        a1 = a1 >= 0.0f ? a1 : 0.01f * a1;   // leaky_relu
        float a2 = acc2[j] + b2[j];
        a2 = a2 >= 0.0f ? a2 : 0.01f * a2;
        float o = a1 + a2;
        acc1[j] = o;                          // reuse acc1 as o[]
        ss += o * o;
    }
    float nv2 = fmaxf(sqrtf(ss), 1e-12f);
    float inv = 1.0f / nv2;
    if (act) {
        #pragma unroll
        for (int j = 0; j < DOUT; j += 4) {
            float4 st = make_float4(acc1[j] * inv, acc1[j + 1] * inv,
                                    acc1[j + 2] * inv, acc1[j + 3] * inv);
            *(float4*)(out + (size_t)v * 240 + out_col + j) = st;
        }
        if (nrm_out) nrm_out[v] = nv2;
    }
}

__global__ void copy_ego_kernel(const float* __restrict__ embed,
                                float* __restrict__ out, int nnodes) {
    int tid = blockIdx.x * blockDim.x + threadIdx.x;
    if (tid >= nnodes * 32) return;
    int v = tid >> 5;
    int c = tid & 31;
    float4 val = *(const float4*)(embed + (size_t)v * 128 + 4 * c);
    *(float4*)(out + (size_t)v * 240 + 4 * c) = val;
}

extern "C" void kernel_launch(void* const* d_in, const int* in_sizes, int n_in,
                              void* d_out, int out_size, void* d_ws, size_t ws_size,
                              hipStream_t stream) {
    const float* embed = (const float*)d_in[0];
    const float* rel   = (const float*)d_in[1];
    const float* pw    = (const float*)d_in[2];
    const float* mw    = (const float*)d_in[3];
    const float* W1_0  = (const float*)d_in[4];
    const float* b1_0  = (const float*)d_in[5];
    const float* W2_0  = (const float*)d_in[6];
    const float* b2_0  = (const float*)d_in[7];
    const float* W1_1  = (const float*)d_in[8];
    const float* b1_1  = (const float*)d_in[9];
    const float* W2_1  = (const float*)d_in[10];
    const float* b2_1  = (const float*)d_in[11];
    const float* W1_2  = (const float*)d_in[12];
    const float* b1_2  = (const float*)d_in[13];
    const float* W1_2b = (const float*)d_in[14];
    const float* b2_2  = (const float*)d_in[15];
    const int* src   = (const int*)d_in[16];
    const int* dst   = (const int*)d_in[17];
    const int* etype = (const int*)d_in[18];
    float* out = (float*)d_out;

    const int n = in_sizes[0] / 128;   // 100000
    const int e = in_sizes[16];        // 1000000

    // workspace (~65 MB), fully rewritten each call
    char* ws = (char*)d_ws;
    float* att_s  = (float*)ws;                        // E
    int*   src_s  = (int*)(att_s + e);                 // E
    int*   de_s   = src_s + e;                         // E (dst | etype<<20)
    float* Nh     = (float*)(de_s + e);                // N*128 (reused per layer)
    int*   rowptr = (int*)(Nh + (size_t)n * 128);      // N+1
    int*   cnt    = rowptr + n + 1;                    // N
    int*   cursor = cnt + n;                           // N
    int*   bsum   = cursor + n;                        // 128
    int*   boff   = bsum + 128;                        // 128
    float* nrm1   = (float*)(boff + 128);              // N
    float* nrm2   = nrm1 + n;                          // N

    const int NB = (n + 1023) / 1024;   // scan blocks (98)

    hipMemsetAsync(cnt, 0, (size_t)(2 * n) * 4, stream);   // cnt + cursor
    hist_kernel<<<(e + 255) / 256, 256, 0, stream>>>(dst, cnt, e);
    scan_block_kernel<<<NB, 1024, 0, stream>>>(cnt, rowptr, bsum, n);
    scan_tops_kernel<<<1, 64, 0, stream>>>(bsum, boff, NB);
    scan_add_kernel<<<NB, 1024, 0, stream>>>(rowptr, boff, n);
    fill_kernel<<<(e + 255) / 256, 256, 0, stream>>>(src, dst, etype, rowptr,
                                                     cursor, src_s, de_s, e);
    edge_att_kernel<<<(e + 3) / 4, 256, 0, stream>>>(
        embed, rel, pw, mw, src_s, de_s, att_s, e);
    softmax_kernel<<<(n + 255) / 256, 256, 0, stream>>>(rowptr, att_s, n);

    int gblocks = (n + 3) / 4;
    int tiles = (n + 63) / 64;          // 1563 node tiles (64 nodes per wave)
    int gemmblocks = (tiles + 3) / 4;   // 4 waves per block, 1 tile per wave
    // ---- layer 0: 128 -> 64, out cols [128,192) ----
    gather_kernel<128, false><<<gblocks, 256, 0, stream>>>(
        embed, 128, nullptr, att_s, src_s, rowptr, Nh, n);
    gemm_kernel<128, 64, false><<<gemmblocks, 256, 0, stream>>>(
        embed, 128, nullptr, Nh, W1_0, b1_0, W2_0, b2_0, out, 128, nrm1, n);
    // ---- layer 1: 64 -> 32, out cols [192,224) ----
    gather_kernel<64, true><<<gblocks, 256, 0, stream>>>(
        out + 128, 240, nrm1, att_s, src_s, rowptr, Nh, n);
    gemm_kernel<64, 32, true><<<gemmblocks, 256, 0, stream>>>(
        out + 128, 240, nrm1, Nh, W1_1, b1_1, W2_1, b2_1, out, 192, nrm2, n);
    // ---- layer 2: 32 -> 16, out cols [224,240) ----
    gather_kernel<32, true><<<gblocks, 256, 0, stream>>>(
        out + 192, 240, nrm2, att_s, src_s, rowptr, Nh, n);
    gemm_kernel<32, 16, true><<<gemmblocks, 256, 0, stream>>>(
        out + 192, 240, nrm2, Nh, W1_2, b1_2, W1_2b, b2_2, out, 224, nullptr, n);

    copy_ego_kernel<<<(n * 32 + 255) / 256, 256, 0, stream>>>(embed, out, n);
}

// Round 7
// 659.369 us; speedup vs baseline: 5.5321x; 1.3784x over previous
//
#include <hip/hip_runtime.h>
#include <math.h>

// ---------------------------------------------------------------------------
// KGAT-HAKE, round 7: gemm = coalesced LDS staging of x1/x2 (64-node tile,
// [64][DIN+1] pad -> conflict-free lane=node reads) + 8-way j-split with
// readfirstlane-forced scalar W addresses (s_load) + lane-local FMA chains.
// N=100000 nodes, E=1000000 edges, R=40 rels, out = N x 240 fp32.
// ---------------------------------------------------------------------------

__global__ void hist_kernel(const int* __restrict__ dst, int* __restrict__ cnt,
                            int nedges) {
    int e = blockIdx.x * blockDim.x + threadIdx.x;
    if (e < nedges) atomicAdd(&cnt[dst[e]], 1);
}

// Per-block inclusive scan of cnt -> rowptr[i+1] (block-local) + block sums.
__global__ __launch_bounds__(1024) void scan_block_kernel(
    const int* __restrict__ cnt, int* __restrict__ rowptr,
    int* __restrict__ bsum, int n) {
    __shared__ int swv[16];
    int tid = threadIdx.x, lane = tid & 63, wid = tid >> 6;
    int i = blockIdx.x * 1024 + tid;
    int v = (i < n) ? cnt[i] : 0;
    #pragma unroll
    for (int off = 1; off < 64; off <<= 1) {
        int t = __shfl_up(v, off, 64);
        if (lane >= off) v += t;
    }
    if (lane == 63) swv[wid] = v;
    __syncthreads();
    if (wid == 0) {
        int s = (lane < 16) ? swv[lane] : 0;
        #pragma unroll
        for (int off = 1; off < 16; off <<= 1) {
            int t = __shfl_up(s, off, 64);
            if (lane >= off) s += t;
        }
        if (lane < 16) swv[lane] = s;
    }
    __syncthreads();
    int offv = wid ? swv[wid - 1] : 0;
    if (i < n) rowptr[i + 1] = v + offv;
    if (tid == 1023) bsum[blockIdx.x] = v + offv;
}

// Exclusive scan of up to 128 block sums (one wave, 2 elems/lane).
__global__ __launch_bounds__(64) void scan_tops_kernel(
    const int* __restrict__ bsum, int* __restrict__ boff, int nb) {
    int l = threadIdx.x;
    int a = (2 * l < nb) ? bsum[2 * l] : 0;
    int b = (2 * l + 1 < nb) ? bsum[2 * l + 1] : 0;
    int s = a + b;
    #pragma unroll
    for (int off = 1; off < 64; off <<= 1) {
        int t = __shfl_up(s, off, 64);
        if (l >= off) s += t;
    }
    int excl = s - (a + b);
    if (2 * l < nb) boff[2 * l] = excl;
    if (2 * l + 1 < nb) boff[2 * l + 1] = excl + a;
}

__global__ __launch_bounds__(1024) void scan_add_kernel(
    int* __restrict__ rowptr, const int* __restrict__ boff, int n) {
    int i = blockIdx.x * 1024 + threadIdx.x;
    if (i < n) rowptr[i + 1] += boff[blockIdx.x];
    if (i == 0) rowptr[0] = 0;
}

// Scatter edge metadata into dst-sorted CSR slots (before scoring).
__global__ void fill_kernel(const int* __restrict__ src, const int* __restrict__ dst,
                            const int* __restrict__ etype,
                            const int* __restrict__ rowptr, int* __restrict__ cursor,
                            int* __restrict__ src_s, int* __restrict__ de_s,
                            int nedges) {
    int e = blockIdx.x * blockDim.x + threadIdx.x;
    if (e >= nedges) return;
    int d = dst[e];
    int slot = rowptr[d] + atomicAdd(&cursor[d], 1);
    src_s[slot] = src[e];
    de_s[slot] = d | (etype[e] << 20);
}

// HAKE edge score over CSR-ordered slots; one wave per edge. No atomics.
__global__ __launch_bounds__(256) void edge_att_kernel(
    const float* __restrict__ embed, const float* __restrict__ rel,
    const float* __restrict__ pw, const float* __restrict__ mw,
    const int* __restrict__ src_s, const int* __restrict__ de_s,
    float* __restrict__ att_s, int nedges)
{
    int k = blockIdx.x * 4 + (threadIdx.x >> 6);
    if (k >= nedges) return;
    int ku = __builtin_amdgcn_readfirstlane(k);
    int lane = threadIdx.x & 63;
    int s = src_s[ku];
    int de = de_s[ku];
    int d = de & 0xFFFFF, r = de >> 20;
    const float* hrow = embed + (size_t)d * 128;
    const float* trow = embed + (size_t)s * 128;
    const float* rrow = rel + (size_t)r * 192;

    float ph = hrow[lane], mh = hrow[64 + lane];
    float pt = trow[lane], mt = trow[64 + lane];
    float pr = rrow[lane];
    float mr = fabsf(rrow[64 + lane]);
    float br = rrow[128 + lane];
    br = fminf(br, 1.0f);
    br = fmaxf(br, -mr);          // where(br < -mr, -mr, br)

    float c = mh * (mr + br) - mt * (1.0f - br);
    float sumsq = c * c;

    // phase/2 = (ph+pr-pt) * PI/(2*EMB_RANGE); |arg| <= 3*pi/2 -> native sin ok
    const float HALF_INV_SCALE = (float)(0.5 * 3.1415926235897933 / 0.21875);
    float psum = fabsf(__sinf((ph + pr - pt) * HALF_INV_SCALE));

    #pragma unroll
    for (int off = 32; off > 0; off >>= 1) {
        sumsq += __shfl_xor(sumsq, off, 64);
        psum  += __shfl_xor(psum, off, 64);
    }
    if (lane == 0)
        att_s[ku] = sqrtf(sumsq) * mw[0] + psum * pw[0];
}

// Per-node softmax over dst-sorted scores (contiguous range per node).
__global__ void softmax_kernel(const int* __restrict__ rowptr,
                               float* __restrict__ att_s, int nnodes) {
    int v = blockIdx.x * blockDim.x + threadIdx.x;
    if (v >= nnodes) return;
    int beg = rowptr[v], end = rowptr[v + 1];
    if (beg == end) return;
    float m = -INFINITY;
    for (int kk = beg; kk < end; ++kk) m = fmaxf(m, att_s[kk]);
    float den = 0.0f;
    for (int kk = beg; kk < end; ++kk) {
        float ex = __expf(att_s[kk] - m);
        att_s[kk] = ex;
        den += ex;
    }
    float inv = 1.0f / den;
    for (int kk = beg; kk < end; ++kk) att_s[kk] *= inv;
}

// CSR gather: Nh[v] = sum_k a_k * node[src_k] (a_k optionally * nrm[src_k]).
// Wave per node; DIN/4 lanes per edge (float4), 4-edge-deep unroll for MLP.
template<int DIN, bool NRM>
__global__ __launch_bounds__(256) void gather_kernel(
    const float* __restrict__ node, int nstride, const float* __restrict__ nrm,
    const float* __restrict__ att_s, const int* __restrict__ src_s,
    const int* __restrict__ rowptr, float* __restrict__ Nh, int nnodes)
{
    constexpr int LPE = DIN / 4;    // lanes per edge row
    constexpr int EP  = 64 / LPE;   // edges in parallel
    constexpr int U   = 4;          // unroll depth
    int v = blockIdx.x * 4 + (threadIdx.x >> 6);
    if (v >= nnodes) return;
    int lane = threadIdx.x & 63;
    int sub = lane / LPE;
    int c = lane % LPE;
    int beg = rowptr[v];
    int deg = rowptr[v + 1] - beg;

    float4 acc = make_float4(0.f, 0.f, 0.f, 0.f);
    for (int kb = 0; kb < deg; kb += 64) {
        int kc = kb + lane;
        bool inr = kc < deg;
        int sv = inr ? src_s[beg + kc] : 0;
        float av = inr ? att_s[beg + kc] : 0.0f;
        if (NRM) av = inr ? av * nrm[sv] : 0.0f;   // fold norm at preload
        int kmax = min(64, deg - kb);
        for (int k0 = 0; k0 < kmax; k0 += U * EP) {
            float a[U];
            const float4* p[U];
            #pragma unroll
            for (int u = 0; u < U; ++u) {
                int kk = k0 + u * EP + sub;
                bool val = kk < kmax;
                int kidx = val ? kk : 0;
                int ssrc = __shfl(sv, kidx, 64);
                float aa = __shfl(av, kidx, 64);
                a[u] = val ? aa : 0.0f;
                p[u] = (const float4*)(node + (size_t)ssrc * nstride + 4 * c);
            }
            float4 rv[U];
            #pragma unroll
            for (int u = 0; u < U; ++u) rv[u] = *p[u];
            #pragma unroll
            for (int u = 0; u < U; ++u) {
                acc.x += a[u] * rv[u].x;
                acc.y += a[u] * rv[u].y;
                acc.z += a[u] * rv[u].z;
                acc.w += a[u] * rv[u].w;
            }
        }
    }
    #pragma unroll
    for (int off = LPE; off < 64; off <<= 1) {
        acc.x += __shfl_xor(acc.x, off, 64);
        acc.y += __shfl_xor(acc.y, off, 64);
        acc.z += __shfl_xor(acc.z, off, 64);
        acc.w += __shfl_xor(acc.w, off, 64);
    }
    if (sub == 0)
        *(float4*)(Nh + (size_t)v * DIN + 4 * c) = acc;
}

// Dual GEMV over a 64-node tile per 512-thread block.
// Phase 1: coalesced staging of x1=(x+Nh), x2=(x*Nh) into padded LDS.
// Phase 2: lane=node; 8 waves split j-range (jh via readfirstlane -> W loads
// are provably scalar s_load); acc = 2*DH independent FMA chains per lane.
// Norm: per-node partial ss across waves via small LDS reduce.
template<int DIN, int DOUT, bool NRM>
__global__ __launch_bounds__(512) void gemm_kernel(
    const float* __restrict__ node, int nstride, const float* __restrict__ nrm_in,
    const float* __restrict__ Nh,
    const float* __restrict__ W1, const float* __restrict__ b1,
    const float* __restrict__ W2, const float* __restrict__ b2,
    float* __restrict__ out, int out_col, float* __restrict__ nrm_out, int nnodes)
{
    constexpr int XS = DIN + 1;          // padded row: lane stride 129 words
    constexpr int DH = DOUT / 8;         // j-range per wave
    __shared__ float sx1[64 * XS], sx2[64 * XS];
    __shared__ float sred[8][64];

    int tid = threadIdx.x;
    int tile0 = blockIdx.x * 64;

    // ---- phase 1: coalesced staging ----
    for (int idx = tid; idx < 64 * (DIN / 4); idx += 512) {
        int row = idx / (DIN / 4), c = idx % (DIN / 4);
        int v = tile0 + row;
        float4 nv4 = make_float4(0.f, 0.f, 0.f, 0.f);
        float4 hv4 = make_float4(0.f, 0.f, 0.f, 0.f);
        if (v < nnodes) {
            nv4 = *(const float4*)(node + (size_t)v * nstride + 4 * c);
            hv4 = *(const float4*)(Nh + (size_t)v * DIN + 4 * c);
            if (NRM) {
                float rn = nrm_in[v];
                nv4.x *= rn; nv4.y *= rn; nv4.z *= rn; nv4.w *= rn;
            }
        }
        float* p1 = sx1 + row * XS + 4 * c;
        float* p2 = sx2 + row * XS + 4 * c;
        p1[0] = nv4.x + hv4.x; p1[1] = nv4.y + hv4.y;
        p1[2] = nv4.z + hv4.z; p1[3] = nv4.w + hv4.w;
        p2[0] = nv4.x * hv4.x; p2[1] = nv4.y * hv4.y;
        p2[2] = nv4.z * hv4.z; p2[3] = nv4.w * hv4.w;
    }
    __syncthreads();

    // ---- phase 2: dual GEMV, lane = node ----
    int lane = tid & 63;
    int jh = __builtin_amdgcn_readfirstlane(tid >> 6);   // SGPR wave id
    int j0 = jh * DH;
    int v = tile0 + lane;
    bool act = v < nnodes;

    float acc1[DH], acc2[DH];
    #pragma unroll
    for (int j = 0; j < DH; ++j) { acc1[j] = 0.f; acc2[j] = 0.f; }

    const float* px1 = sx1 + lane * XS;
    const float* px2 = sx2 + lane * XS;
    #pragma unroll 1
    for (int ic = 0; ic < DIN; ic += 8) {
        float x1c[8], x2c[8];
        #pragma unroll
        for (int t = 0; t < 8; ++t) {
            x1c[t] = px1[ic + t];
            x2c[t] = px2[ic + t];
        }
        #pragma unroll
        for (int j = 0; j < DH; ++j) {
            // scalar addresses: kernel arg + SGPR j0 + loop constants -> s_load
            const float* w1 = W1 + (size_t)(j0 + j) * DIN + ic;
            const float* w2 = W2 + (size_t)(j0 + j) * DIN + ic;
            #pragma unroll
            for (int t = 0; t < 8; ++t) {
                acc1[j] = fmaf(x1c[t], w1[t], acc1[j]);
                acc2[j] = fmaf(x2c[t], w2[t], acc2[j]);
            }
        }
    }

    float o[DH];
    float ss = 0.0f;
    #pragma unroll
    for (int j = 0; j < DH; ++j) {
        float a1 = acc1[j] + b1[j0 + j];
        a1 = a1 >= 0.0f ? a1 : 0.01f * a1;   // leaky_relu
        float a2 = acc2[j] + b2[j0 + j];
        a2 = a2 >= 0.0f ? a2 : 0.01f * a2;
        o[j] = a1 + a2;
        ss += o[j] * o[j];
    }
    sred[jh][lane] = ss;
    __syncthreads();
    float tot = 0.0f;
    #pragma unroll
    for (int q = 0; q < 8; ++q) tot += sred[q][lane];
    float nv2 = fmaxf(sqrtf(tot), 1e-12f);
    float inv = 1.0f / nv2;
    if (act) {
        float* po = out + (size_t)v * 240 + out_col + j0;
        if (DH >= 4) {
            #pragma unroll
            for (int j = 0; j < DH; j += 4) {
                float4 st = make_float4(o[j] * inv, o[j + 1] * inv,
                                        o[j + 2] * inv, o[j + 3] * inv);
                *(float4*)(po + j) = st;
            }
        } else {
            #pragma unroll
            for (int j = 0; j < DH; ++j) po[j] = o[j] * inv;
        }
        if (nrm_out && jh == 0) nrm_out[v] = nv2;
    }
}

__global__ void copy_ego_kernel(const float* __restrict__ embed,
                                float* __restrict__ out, int nnodes) {
    int tid = blockIdx.x * blockDim.x + threadIdx.x;
    if (tid >= nnodes * 32) return;
    int v = tid >> 5;
    int c = tid & 31;
    float4 val = *(const float4*)(embed + (size_t)v * 128 + 4 * c);
    *(float4*)(out + (size_t)v * 240 + 4 * c) = val;
}

extern "C" void kernel_launch(void* const* d_in, const int* in_sizes, int n_in,
                              void* d_out, int out_size, void* d_ws, size_t ws_size,
                              hipStream_t stream) {
    const float* embed = (const float*)d_in[0];
    const float* rel   = (const float*)d_in[1];
    const float* pw    = (const float*)d_in[2];
    const float* mw    = (const float*)d_in[3];
    const float* W1_0  = (const float*)d_in[4];
    const float* b1_0  = (const float*)d_in[5];
    const float* W2_0  = (const float*)d_in[6];
    const float* b2_0  = (const float*)d_in[7];
    const float* W1_1  = (const float*)d_in[8];
    const float* b1_1  = (const float*)d_in[9];
    const float* W2_1  = (const float*)d_in[10];
    const float* b2_1  = (const float*)d_in[11];
    const float* W1_2  = (const float*)d_in[12];
    const float* b1_2  = (const float*)d_in[13];
    const float* W1_2b = (const float*)d_in[14];
    const float* b2_2  = (const float*)d_in[15];
    const int* src   = (const int*)d_in[16];
    const int* dst   = (const int*)d_in[17];
    const int* etype = (const int*)d_in[18];
    float* out = (float*)d_out;

    const int n = in_sizes[0] / 128;   // 100000
    const int e = in_sizes[16];        // 1000000

    // workspace (~65 MB), fully rewritten each call
    char* ws = (char*)d_ws;
    float* att_s  = (float*)ws;                        // E
    int*   src_s  = (int*)(att_s + e);                 // E
    int*   de_s   = src_s + e;                         // E (dst | etype<<20)
    float* Nh     = (float*)(de_s + e);                // N*128 (reused per layer)
    int*   rowptr = (int*)(Nh + (size_t)n * 128);      // N+1
    int*   cnt    = rowptr + n + 1;                    // N
    int*   cursor = cnt + n;                           // N
    int*   bsum   = cursor + n;                        // 128
    int*   boff   = bsum + 128;                        // 128
    float* nrm1   = (float*)(boff + 128);              // N
    float* nrm2   = nrm1 + n;                          // N

    const int NB = (n + 1023) / 1024;   // scan blocks (98)

    hipMemsetAsync(cnt, 0, (size_t)(2 * n) * 4, stream);   // cnt + cursor
    hist_kernel<<<(e + 255) / 256, 256, 0, stream>>>(dst, cnt, e);
    scan_block_kernel<<<NB, 1024, 0, stream>>>(cnt, rowptr, bsum, n);
    scan_tops_kernel<<<1, 64, 0, stream>>>(bsum, boff, NB);
    scan_add_kernel<<<NB, 1024, 0, stream>>>(rowptr, boff, n);
    fill_kernel<<<(e + 255) / 256, 256, 0, stream>>>(src, dst, etype, rowptr,
                                                     cursor, src_s, de_s, e);
    edge_att_kernel<<<(e + 3) / 4, 256, 0, stream>>>(
        embed, rel, pw, mw, src_s, de_s, att_s, e);
    softmax_kernel<<<(n + 255) / 256, 256, 0, stream>>>(rowptr, att_s, n);

    int gblocks = (n + 3) / 4;
    int tiles = (n + 63) / 64;          // 1563 node tiles (64 nodes per block)
    // ---- layer 0: 128 -> 64, out cols [128,192) ----
    gather_kernel<128, false><<<gblocks, 256, 0, stream>>>(
        embed, 128, nullptr, att_s, src_s, rowptr, Nh, n);
    gemm_kernel<128, 64, false><<<tiles, 512, 0, stream>>>(
        embed, 128, nullptr, Nh, W1_0, b1_0, W2_0, b2_0, out, 128, nrm1, n);
    // ---- layer 1: 64 -> 32, out cols [192,224) ----
    gather_kernel<64, true><<<gblocks, 256, 0, stream>>>(
        out + 128, 240, nrm1, att_s, src_s, rowptr, Nh, n);
    gemm_kernel<64, 32, true><<<tiles, 512, 0, stream>>>(
        out + 128, 240, nrm1, Nh, W1_1, b1_1, W2_1, b2_1, out, 192, nrm2, n);
    // ---- layer 2: 32 -> 16, out cols [224,240) ----
    gather_kernel<32, true><<<gblocks, 256, 0, stream>>>(
        out + 192, 240, nrm2, att_s, src_s, rowptr, Nh, n);
    gemm_kernel<32, 16, true><<<tiles, 512, 0, stream>>>(
        out + 192, 240, nrm2, Nh, W1_2, b1_2, W1_2b, b2_2, out, 224, nullptr, n);

    copy_ego_kernel<<<(n * 32 + 255) / 256, 256, 0, stream>>>(embed, out, n);
}